// Round 4
// baseline (427.958 us; speedup 1.0000x reference)
//
#include <hip/hip_runtime.h>
#include <math.h>

#define AS1 __attribute__((address_space(1)))
#define AS3 __attribute__((address_space(3)))

typedef unsigned short u16;
typedef signed char i8;
typedef short bf16x8 __attribute__((ext_vector_type(8)));
typedef float f32x4 __attribute__((ext_vector_type(4)));
typedef int i32x4 __attribute__((ext_vector_type(4)));

static constexpr int BB = 64, T = 256, C = 1024, H = 16, HD = 64;
static constexpr int M = BB * T;          // 16384 token rows
static constexpr float EPSF = 1e-5f;

// ---- workspace layout (bytes) ----
static constexpr size_t W8_OFF   = 0;                    // 4 x 1M i8 = 4 MiB ternary weights
static constexpr size_t XQ8_OFF  = 4ull  << 20;          // 16M i8 = 16 MiB (reused for yq)
static constexpr size_t RSX_OFF  = 20ull << 20;          // 16384 f32
static constexpr size_t RSY_OFF  = (20ull << 20) + (64 << 10);
static constexpr size_t WSUM_OFF = (20ull << 20) + (128 << 10);   // 4 f64
static constexpr size_t WPART_OFF= WSUM_OFF + 64;                 // 256 f64
static constexpr size_t QB_OFF   = 21ull << 20;          // 32 MiB bf16
static constexpr size_t KB_OFF   = 53ull << 20;          // 32 MiB bf16
static constexpr size_t VT_OFF   = 85ull << 20;          // 32 MiB bf16 V^T [b][h*64+d][tloc]

// round-to-nearest-even f32 -> bf16 bits (finite inputs)
__device__ __forceinline__ u16 f2bf_rne(float f) {
    unsigned x = __float_as_uint(f);
    unsigned r = x + 0x7FFF + ((x >> 16) & 1);
    return (u16)(r >> 16);
}

// ---------------- weight |w| sum, stage 1 (deterministic, f64) ----------------
__global__ __launch_bounds__(256) void wsum1_kernel(const float* __restrict__ Wq,
    const float* __restrict__ Wk, const float* __restrict__ Wv,
    const float* __restrict__ Wp, double* __restrict__ wpart)
{
    const int mat = blockIdx.x >> 6;
    const float* W = (mat == 0) ? Wq : (mat == 1) ? Wk : (mat == 2) ? Wv : Wp;
    const int t = threadIdx.x;
    const int base = (blockIdx.x & 63) * 256 + t;
    double s = 0.0;
    for (int i = 0; i < 64; ++i) s += (double)fabsf(W[base + (i << 14)]);
    #pragma unroll
    for (int off = 32; off >= 1; off >>= 1) s += __shfl_down(s, off);
    __shared__ double red[4];
    if ((t & 63) == 0) red[t >> 6] = s;
    __syncthreads();
    if (t == 0) wpart[blockIdx.x] = red[0] + red[1] + red[2] + red[3];
}

__global__ __launch_bounds__(256) void wsum2_kernel(const double* __restrict__ wpart,
                                                    double* __restrict__ wsum)
{
    const int t = threadIdx.x;
    double s = wpart[t];
    #pragma unroll
    for (int off = 32; off >= 1; off >>= 1) s += __shfl_down(s, off);
    if ((t & 63) == 0) wsum[t >> 6] = s;
}

// ---------------- ternary weight quantization -> int8 ----------------
__global__ __launch_bounds__(256) void wquant_kernel(const float* __restrict__ Wq,
    const float* __restrict__ Wk, const float* __restrict__ Wv,
    const float* __restrict__ Wp, const double* __restrict__ wsum,
    i8* __restrict__ w8)
{
    const int mat = blockIdx.x >> 10;
    const float* W = (mat == 0) ? Wq : (mat == 1) ? Wk : (mat == 2) ? Wv : Wp;
    const float mean = (float)(wsum[mat] * (1.0 / 1048576.0));
    const float s = 1.0f / fmaxf(mean, EPSF);
    const int idx = (blockIdx.x & 1023) * 256 + threadIdx.x;   // float4 / char4 index
    float4 w = ((const float4*)W)[idx];
    char4 o;
    o.x = (i8)(int)fminf(fmaxf(rintf(w.x * s), -1.f), 1.f);
    o.y = (i8)(int)fminf(fmaxf(rintf(w.y * s), -1.f), 1.f);
    o.z = (i8)(int)fminf(fmaxf(rintf(w.z * s), -1.f), 1.f);
    o.w = (i8)(int)fminf(fmaxf(rintf(w.w * s), -1.f), 1.f);
    ((char4*)(w8 + (size_t)mat * 1048576))[idx] = o;
}

// ---------------- per-token activation quantization -> int8 ----------------
__global__ __launch_bounds__(256) void actquant_kernel(const float* __restrict__ x,
    i8* __restrict__ xq, float* __restrict__ rs)
{
    const int row = blockIdx.x;
    const int t = threadIdx.x;
    float4 v = ((const float4*)(x + (size_t)row * C))[t];
    float m = fmaxf(fmaxf(fabsf(v.x), fabsf(v.y)), fmaxf(fabsf(v.z), fabsf(v.w)));
    #pragma unroll
    for (int off = 32; off >= 1; off >>= 1) m = fmaxf(m, __shfl_down(m, off));
    __shared__ float red[4];
    if ((t & 63) == 0) red[t >> 6] = m;
    __syncthreads();
    float mm = fmaxf(fmaxf(red[0], red[1]), fmaxf(red[2], red[3]));
    mm = fmaxf(mm, EPSF);
    const float s = 127.0f / mm;
    if (t == 0) rs[row] = mm / 127.0f;
    char4 o;
    o.x = (i8)(int)fminf(fmaxf(rintf(v.x * s), -128.f), 127.f);
    o.y = (i8)(int)fminf(fmaxf(rintf(v.y * s), -128.f), 127.f);
    o.z = (i8)(int)fminf(fmaxf(rintf(v.z * s), -128.f), 127.f);
    o.w = (i8)(int)fminf(fmaxf(rintf(v.w * s), -128.f), 127.f);
    ((char4*)(xq + (size_t)row * C))[t] = o;
}

// ---------------- int8 MFMA GEMM: out[M,1024] = A[M,1024] x W[1024,1024]^T ----------------
// 256x256 tile, BK=64, 8 waves (2Mx4N), per-wave 128x64 output.
// 4-deep LDS ring (4 x 32KB = 128KB), stage t+2 while computing t.
// ONE barrier per K-tile: the 4-deep ring means buffer (t+2)&3 was last read
// two barriers ago, so intra-tile barriers are unnecessary -- dropping them
// lets waves desync so one wave's ds_reads overlap another's MFMAs.
// Plain C++ ds_reads (compiler emits fine-grained lgkmcnt; m97 precedent),
// counted vmcnt(4) never drains in main loop, setprio around MFMA cluster.
// LDS XOR-swizzle via inverse-swizzled global source + swizzled ds_read.
// Exact i32 accumulation, numerics unchanged.
template<bool QKV, int NNB>
__global__ __launch_bounds__(512, 2) void gemm_kernel(const i8* __restrict__ A,
    const i8* __restrict__ w8, const float* __restrict__ rs_row,
    const double* __restrict__ wsum, u16* __restrict__ qb, u16* __restrict__ kb,
    u16* __restrict__ vt, float* __restrict__ outp, const float* __restrict__ bias)
{
    constexpr int K = 1024, N = 1024;
    constexpr int NT = 16;                           // K-tiles of 64
    __shared__ __align__(16) i8 Asm[4][256 * 64];    // 64 KiB
    __shared__ __align__(16) i8 Bsm[4][256 * 64];    // 64 KiB

    const int t = threadIdx.x;

    // bijective XCD swizzle (nwg % 8 == 0 for both grids)
    const int nwg = NNB * 64;
    const int wg = (int)blockIdx.x;
    const int swz = (wg & 7) * (nwg >> 3) + (wg >> 3);
    const int mb = swz / NNB, nb = swz % NNB;
    const int m0 = mb * 256;
    const int mat = QKV ? (nb >> 2) : 3;
    const int n0m = QKV ? ((nb & 3) * 256) : (nb * 256);   // col base within mat
    const i8* Bw = w8 + (size_t)mat * 1048576;

    const int lane = t & 63, wv = t >> 6;
    const int wm = wv >> 2, wn = wv & 3;             // 2x4 wave grid
    const int mr = lane & 15, quad = lane >> 4;

    // staging granules: g1=t, g2=t+512 (16B each, linear LDS dest).
    // logical source offset = inverse swizzle of the physical byte address.
    const int g1 = t, g2 = t + 512;
    const int L1 = (g1 * 16) ^ (((g1 >> 3) & 7) << 4);
    const int L2 = (g2 * 16) ^ (((g2 >> 3) & 7) << 4);
    const i8* a1 = A  + (size_t)(m0  + (L1 >> 6)) * K + (L1 & 63);
    const i8* a2 = A  + (size_t)(m0  + (L2 >> 6)) * K + (L2 & 63);
    const i8* b1 = Bw + (size_t)(n0m + (L1 >> 6)) * K + (L1 & 63);
    const i8* b2 = Bw + (size_t)(n0m + (L2 >> 6)) * K + (L2 & 63);

    // swizzled fragment read offsets (vvs constant per thread: rows are 16-aligned)
    const int vvs = (mr >> 1) & 7;
    int aoff[8], boff[4];
    #pragma unroll
    for (int m = 0; m < 8; ++m)
        aoff[m] = ((wm * 128 + m * 16 + mr) * 64 + quad * 16) ^ (vvs << 4);
    #pragma unroll
    for (int n = 0; n < 4; ++n)
        boff[n] = ((wn * 64 + n * 16 + mr) * 64 + quad * 16) ^ (vvs << 4);

    i32x4 acc[8][4];
    #pragma unroll
    for (int m = 0; m < 8; ++m)
        #pragma unroll
        for (int n = 0; n < 4; ++n) acc[m][n] = (i32x4){0, 0, 0, 0};

    // prologue: stage tiles 0 and 1
    #pragma unroll
    for (int p = 0; p < 2; ++p) {
        const int k0 = p * 64;
        __builtin_amdgcn_global_load_lds((const AS1 void*)(a1 + k0), (AS3 void*)&Asm[p][g1 * 16], 16, 0, 0);
        __builtin_amdgcn_global_load_lds((const AS1 void*)(a2 + k0), (AS3 void*)&Asm[p][g2 * 16], 16, 0, 0);
        __builtin_amdgcn_global_load_lds((const AS1 void*)(b1 + k0), (AS3 void*)&Bsm[p][g1 * 16], 16, 0, 0);
        __builtin_amdgcn_global_load_lds((const AS1 void*)(b2 + k0), (AS3 void*)&Bsm[p][g2 * 16], 16, 0, 0);
    }
    asm volatile("s_waitcnt vmcnt(4)" ::: "memory");   // tile 0 landed; tile 1 in flight
    __builtin_amdgcn_s_barrier();
    __builtin_amdgcn_sched_barrier(0);

    for (int tt = 0; tt < NT; ++tt) {
        const i8* Ac = Asm[tt & 3];
        const i8* Bc = Bsm[tt & 3];
        i8* An = Asm[(tt + 2) & 3];
        i8* Bn = Bsm[(tt + 2) & 3];
        const int kn = (tt + 2) * 64;

        // issue next-next tile's staging first (T14 issue-early)
        if (tt < NT - 2) {
            __builtin_amdgcn_global_load_lds((const AS1 void*)(a1 + kn), (AS3 void*)&An[g1 * 16], 16, 0, 0);
            __builtin_amdgcn_global_load_lds((const AS1 void*)(a2 + kn), (AS3 void*)&An[g2 * 16], 16, 0, 0);
            __builtin_amdgcn_global_load_lds((const AS1 void*)(b1 + kn), (AS3 void*)&Bn[g1 * 16], 16, 0, 0);
            __builtin_amdgcn_global_load_lds((const AS1 void*)(b2 + kn), (AS3 void*)&Bn[g2 * 16], 16, 0, 0);
        }

        // fragment reads: plain loads -- compiler interleaves lgkmcnt with MFMAs
        i32x4 af[8], bf[4];
        #pragma unroll
        for (int m = 0; m < 8; ++m) af[m] = *(const i32x4*)&Ac[aoff[m]];
        #pragma unroll
        for (int n = 0; n < 4; ++n) bf[n] = *(const i32x4*)&Bc[boff[n]];

        __builtin_amdgcn_s_setprio(1);
        #pragma unroll
        for (int m = 0; m < 8; ++m)
            #pragma unroll
            for (int n = 0; n < 4; ++n)
                acc[m][n] = __builtin_amdgcn_mfma_i32_16x16x64_i8(af[m], bf[n], acc[m][n], 0, 0, 0);
        __builtin_amdgcn_s_setprio(0);

        // tile boundary: tile t+1 must have landed; keep t+2's 4 loads in flight
        if (tt < NT - 2) {
            asm volatile("s_waitcnt vmcnt(4)" ::: "memory");
        } else if (tt < NT - 1) {
            asm volatile("s_waitcnt vmcnt(0)" ::: "memory");
        }
        __builtin_amdgcn_s_barrier();
        __builtin_amdgcn_sched_barrier(0);
    }

    float wsc = fmaxf((float)(wsum[mat] * (1.0 / 1048576.0)), EPSF);
    if (QKV && mat == 0) wsc *= 0.125f;              // fold 1/sqrt(hd) into q scale

    if (QKV && mat == 2) {
        // V^T store: vt[(b*1024 + col)*256 + tloc], 4 consecutive tokens per ushort4
        #pragma unroll
        for (int m = 0; m < 8; ++m) {
            const int gr0 = m0 + wm * 128 + m * 16 + quad * 4;
            const int bbi = gr0 >> 8, tl = gr0 & 255;
            const float4 rs4 = *(const float4*)(rs_row + gr0);
            #pragma unroll
            for (int n = 0; n < 4; ++n) {
                const int gcol = n0m + wn * 64 + n * 16 + mr;
                ushort4 o;
                o.x = f2bf_rne((float)acc[m][n][0] * rs4.x * wsc);
                o.y = f2bf_rne((float)acc[m][n][1] * rs4.y * wsc);
                o.z = f2bf_rne((float)acc[m][n][2] * rs4.z * wsc);
                o.w = f2bf_rne((float)acc[m][n][3] * rs4.w * wsc);
                *(ushort4*)(vt + (size_t)(bbi * 1024 + gcol) * 256 + tl) = o;
            }
        }
        return;
    }

    u16* ob = QKV ? ((mat == 0) ? qb : kb) : nullptr;
    #pragma unroll
    for (int m = 0; m < 8; ++m) {
        const int gr0 = m0 + wm * 128 + m * 16 + quad * 4;
        #pragma unroll
        for (int r = 0; r < 4; ++r) {
            const int grow = gr0 + r;
            const float sc = rs_row[grow] * wsc;
            #pragma unroll
            for (int n = 0; n < 4; ++n) {
                const int gcol = n0m + wn * 64 + n * 16 + mr;
                const float val = (float)acc[m][n][r] * sc;
                if (QKV) {
                    ob[(size_t)grow * N + gcol] = f2bf_rne(val);
                } else {
                    outp[(size_t)grow * N + gcol] = val + bias[gcol];
                }
            }
        }
    }
}

// ---------------- LDS-free MFMA flash attention ----------------
// block = (b,h,qtile); wave = 16 q-rows. S^T = K Q^T (C layout: row=j, col=q)
// -> softmax reduces over regs+quads (2 shuffles) -> P^T->A-frag via 8
// shuffles + 4 selects per 32-j chunk -> O = P V with V^T B-frags from global.
// r3: keep r2's XCD-co-locating grid remap (FETCH 98->49 MB, K/V L2-resident)
// but revert to the r1 low-pressure body: r2's register double-buffer pushed
// VGPR 60->68, crossing the 64-VGPR occupancy step (8->4 waves/SIMD,
// Occupancy 38->16%) and cost +37us on a latency-bound kernel. TLP is the
// latency-hiding mechanism here; launch_bounds(256,8) pins VGPR<=64.
__global__ __launch_bounds__(256, 8) void attn_kernel(const u16* __restrict__ qb,
    const u16* __restrict__ kb, const u16* __restrict__ vt, float* __restrict__ y)
{
    const int t = threadIdx.x;
    const int i = (int)blockIdx.x;
    const int qt = 3 - ((i >> 3) & 3);               // heavy qtiles first per bh group
    const int bh = ((i >> 5) << 3) | (i & 7);        // 4 qt-blocks of a bh: same XCD, 8 apart
    const int b = bh >> 4, h = bh & 15;
    const int w = t >> 6, lane = t & 63;
    const int cl = lane & 15, quad = lane >> 4;
    const size_t gb = (size_t)(b * T) * 1024 + h * 64;             // q/k row-major base
    const u16* vtb = vt + (size_t)(b * 1024 + h * 64) * 256;       // V^T base

    const int qrow = qt * 64 + w * 16;
    const int jtiles = (qrow >> 4) + 1;              // causal: j-tiles 0..jtiles-1

    const u16* qrp = qb + gb + (size_t)(qrow + cl) * 1024 + quad * 8;
    bf16x8 qf0 = *(const bf16x8*)qrp;                // B-frag: n=q, k=d
    bf16x8 qf1 = *(const bf16x8*)(qrp + 32);

    f32x4 Sp[16];
    #pragma unroll
    for (int i2 = 0; i2 < 16; ++i2) Sp[i2] = (f32x4){0.f, 0.f, 0.f, 0.f};

    // --- S^T = K Q^T: A-frag m=j (lane cl = j-local), k=d ---
    const u16* krp = kb + gb + (size_t)cl * 1024 + quad * 8;
    #pragma unroll
    for (int jt = 0; jt < 16; ++jt) {
        if (jt < jtiles) {
            const u16* kp = krp + (size_t)(jt * 16) * 1024;
            bf16x8 kf0 = *(const bf16x8*)kp;
            bf16x8 kf1 = *(const bf16x8*)(kp + 32);
            Sp[jt] = __builtin_amdgcn_mfma_f32_16x16x32_bf16(kf0, qf0, Sp[jt], 0, 0, 0);
            Sp[jt] = __builtin_amdgcn_mfma_f32_16x16x32_bf16(kf1, qf1, Sp[jt], 0, 0, 0);
            if (jt == jtiles - 1) {                  // diagonal: mask j > q
                #pragma unroll
                for (int r = 0; r < 4; ++r)
                    if (quad * 4 + r > cl) Sp[jt][r] = -INFINITY;
            }
        }
    }

    // --- softmax over j (regs x quads); q = cl is lane-resident ---
    float mx = -INFINITY;
    #pragma unroll
    for (int jt = 0; jt < 16; ++jt) if (jt < jtiles) {
        #pragma unroll
        for (int r = 0; r < 4; ++r) mx = fmaxf(mx, Sp[jt][r]);
    }
    mx = fmaxf(mx, __shfl_xor(mx, 16));
    mx = fmaxf(mx, __shfl_xor(mx, 32));
    float l = 0.f;
    #pragma unroll
    for (int jt = 0; jt < 16; ++jt) if (jt < jtiles) {
        #pragma unroll
        for (int r = 0; r < 4; ++r) {
            float p = __expf(Sp[jt][r] - mx);
            Sp[jt][r] = p;
            l += p;
        }
    }
    l += __shfl_xor(l, 16);
    l += __shfl_xor(l, 32);

    // --- O = P V: A-frag built in-register from P^T via shuffles ---
    f32x4 O[4];
    #pragma unroll
    for (int i2 = 0; i2 < 4; ++i2) O[i2] = (f32x4){0.f, 0.f, 0.f, 0.f};

    const int s01 = ((quad & 1) << 5) + cl;          // src lane for frag slots 0-3
    const bool lo = quad < 2;                        // dest quads 0,1 use tile 2jc
    #pragma unroll
    for (int jc = 0; jc < 8; ++jc) {
        if (jc * 2 < jtiles) {
            int pk[2][2];                            // [tile][reg-pair] bf16x2
            #pragma unroll
            for (int s = 0; s < 2; ++s) {
                const f32x4 v = Sp[jc * 2 + s];      // tile >= jtiles is all-zero
                pk[s][0] = (int)((unsigned)f2bf_rne(v[0]) | ((unsigned)f2bf_rne(v[1]) << 16));
                pk[s][1] = (int)((unsigned)f2bf_rne(v[2]) | ((unsigned)f2bf_rne(v[3]) << 16));
            }
            int a0 = __shfl(pk[0][0], s01),      a1 = __shfl(pk[0][1], s01);
            int a2 = __shfl(pk[0][0], s01 + 16), a3 = __shfl(pk[0][1], s01 + 16);
            int b0 = __shfl(pk[1][0], s01),      b1 = __shfl(pk[1][1], s01);
            int b2 = __shfl(pk[1][0], s01 + 16), b3 = __shfl(pk[1][1], s01 + 16);
            union { int i[4]; bf16x8 v; } af;
            af.i[0] = lo ? a0 : b0;
            af.i[1] = lo ? a1 : b1;
            af.i[2] = lo ? a2 : b2;
            af.i[3] = lo ? a3 : b3;
            const u16* vp = vtb + (size_t)cl * 256 + jc * 32 + quad * 8;
            #pragma unroll
            for (int dt = 0; dt < 4; ++dt) {
                bf16x8 vf = *(const bf16x8*)(vp + (size_t)dt * 16 * 256);
                O[dt] = __builtin_amdgcn_mfma_f32_16x16x32_bf16(af.v, vf, O[dt], 0, 0, 0);
            }
        }
    }

    // --- normalize + store: O row = q-local = quad*4+r, col = d = dt*16+cl ---
    float inv[4];
    #pragma unroll
    for (int r = 0; r < 4; ++r) inv[r] = 1.0f / __shfl(l, quad * 4 + r);
    #pragma unroll
    for (int dt = 0; dt < 4; ++dt)
        #pragma unroll
        for (int r = 0; r < 4; ++r)
            y[gb + (size_t)(qrow + quad * 4 + r) * 1024 + dt * 16 + cl] = O[dt][r] * inv[r];
}

extern "C" void kernel_launch(void* const* d_in, const int* in_sizes, int n_in,
                              void* d_out, int out_size, void* d_ws, size_t ws_size,
                              hipStream_t stream) {
    (void)in_sizes; (void)n_in; (void)out_size; (void)ws_size;
    const float* x  = (const float*)d_in[0];
    const float* Wq = (const float*)d_in[1];
    const float* Wk = (const float*)d_in[2];
    const float* Wv = (const float*)d_in[3];
    const float* Wp = (const float*)d_in[4];
    const float* bp = (const float*)d_in[5];
    float* out = (float*)d_out;
    char* ws = (char*)d_ws;

    i8*     w8   = (i8*)(ws + W8_OFF);
    i8*     xq8  = (i8*)(ws + XQ8_OFF);
    float*  rsx  = (float*)(ws + RSX_OFF);
    float*  rsy  = (float*)(ws + RSY_OFF);
    double* wsum = (double*)(ws + WSUM_OFF);
    double* wpart= (double*)(ws + WPART_OFF);
    u16*    qb   = (u16*)(ws + QB_OFF);
    u16*    kb   = (u16*)(ws + KB_OFF);
    u16*    vt   = (u16*)(ws + VT_OFF);

    wsum1_kernel<<<256, 256, 0, stream>>>(Wq, Wk, Wv, Wp, wpart);
    wsum2_kernel<<<1, 256, 0, stream>>>(wpart, wsum);
    wquant_kernel<<<4096, 256, 0, stream>>>(Wq, Wk, Wv, Wp, wsum, w8);
    actquant_kernel<<<M, 256, 0, stream>>>(x, xq8, rsx);

    // fused q/k/v: 3 mats x 4 n-blocks (256 cols) x 64 m-blocks, 512 thr, 256^2 tiles
    gemm_kernel<true, 12><<<768, 512, 0, stream>>>(xq8, w8, rsx, wsum, qb, kb, vt, nullptr, nullptr);

    attn_kernel<<<4 * 1024, 256, 0, stream>>>(qb, kb, vt, out);   // y -> d_out (scratch)

    actquant_kernel<<<M, 256, 0, stream>>>(out, xq8, rsy);        // y -> yq8
    gemm_kernel<false, 4><<<256, 512, 0, stream>>>(xq8, w8, rsy, wsum, nullptr, nullptr, nullptr, out, bp);
}

// Round 5
// 350.155 us; speedup vs baseline: 1.2222x; 1.2222x over previous
//
#include <hip/hip_runtime.h>
#include <math.h>

#define AS1 __attribute__((address_space(1)))
#define AS3 __attribute__((address_space(3)))

typedef unsigned short u16;
typedef signed char i8;
typedef short bf16x8 __attribute__((ext_vector_type(8)));
typedef float f32x4 __attribute__((ext_vector_type(4)));
typedef int i32x4 __attribute__((ext_vector_type(4)));

static constexpr int BB = 64, T = 256, C = 1024, H = 16, HD = 64;
static constexpr int M = BB * T;          // 16384 token rows
static constexpr float EPSF = 1e-5f;

// ---- workspace layout (bytes) ----
static constexpr size_t W8_OFF   = 0;                    // 4 x 1M i8 = 4 MiB ternary weights
static constexpr size_t XQ8_OFF  = 4ull  << 20;          // 16M i8 = 16 MiB (reused for yq)
static constexpr size_t RSX_OFF  = 20ull << 20;          // 16384 f32
static constexpr size_t RSY_OFF  = (20ull << 20) + (64 << 10);
static constexpr size_t WSUM_OFF = (20ull << 20) + (128 << 10);   // 4 f64
static constexpr size_t WPART_OFF= WSUM_OFF + 64;                 // 256 f64
static constexpr size_t QB_OFF   = 21ull << 20;          // 32 MiB bf16
static constexpr size_t KB_OFF   = 53ull << 20;          // 32 MiB bf16
static constexpr size_t VT_OFF   = 85ull << 20;          // 32 MiB bf16 V^T [b][h*64+d][tloc]

// round-to-nearest-even f32 -> bf16 bits (finite inputs)
__device__ __forceinline__ u16 f2bf_rne(float f) {
    unsigned x = __float_as_uint(f);
    unsigned r = x + 0x7FFF + ((x >> 16) & 1);
    return (u16)(r >> 16);
}

// ---------------- weight |w| sum, stage 1 (deterministic, f64) ----------------
__global__ __launch_bounds__(256) void wsum1_kernel(const float* __restrict__ Wq,
    const float* __restrict__ Wk, const float* __restrict__ Wv,
    const float* __restrict__ Wp, double* __restrict__ wpart)
{
    const int mat = blockIdx.x >> 6;
    const float* W = (mat == 0) ? Wq : (mat == 1) ? Wk : (mat == 2) ? Wv : Wp;
    const int t = threadIdx.x;
    const int base = (blockIdx.x & 63) * 256 + t;
    double s = 0.0;
    for (int i = 0; i < 64; ++i) s += (double)fabsf(W[base + (i << 14)]);
    #pragma unroll
    for (int off = 32; off >= 1; off >>= 1) s += __shfl_down(s, off);
    __shared__ double red[4];
    if ((t & 63) == 0) red[t >> 6] = s;
    __syncthreads();
    if (t == 0) wpart[blockIdx.x] = red[0] + red[1] + red[2] + red[3];
}

__global__ __launch_bounds__(256) void wsum2_kernel(const double* __restrict__ wpart,
                                                    double* __restrict__ wsum)
{
    const int t = threadIdx.x;
    double s = wpart[t];
    #pragma unroll
    for (int off = 32; off >= 1; off >>= 1) s += __shfl_down(s, off);
    if ((t & 63) == 0) wsum[t >> 6] = s;
}

// ---------------- ternary weight quantization -> int8 ----------------
__global__ __launch_bounds__(256) void wquant_kernel(const float* __restrict__ Wq,
    const float* __restrict__ Wk, const float* __restrict__ Wv,
    const float* __restrict__ Wp, const double* __restrict__ wsum,
    i8* __restrict__ w8)
{
    const int mat = blockIdx.x >> 10;
    const float* W = (mat == 0) ? Wq : (mat == 1) ? Wk : (mat == 2) ? Wv : Wp;
    const float mean = (float)(wsum[mat] * (1.0 / 1048576.0));
    const float s = 1.0f / fmaxf(mean, EPSF);
    const int idx = (blockIdx.x & 1023) * 256 + threadIdx.x;   // float4 / char4 index
    float4 w = ((const float4*)W)[idx];
    char4 o;
    o.x = (i8)(int)fminf(fmaxf(rintf(w.x * s), -1.f), 1.f);
    o.y = (i8)(int)fminf(fmaxf(rintf(w.y * s), -1.f), 1.f);
    o.z = (i8)(int)fminf(fmaxf(rintf(w.z * s), -1.f), 1.f);
    o.w = (i8)(int)fminf(fmaxf(rintf(w.w * s), -1.f), 1.f);
    ((char4*)(w8 + (size_t)mat * 1048576))[idx] = o;
}

// ---------------- per-token activation quantization -> int8 ----------------
__global__ __launch_bounds__(256) void actquant_kernel(const float* __restrict__ x,
    i8* __restrict__ xq, float* __restrict__ rs)
{
    const int row = blockIdx.x;
    const int t = threadIdx.x;
    float4 v = ((const float4*)(x + (size_t)row * C))[t];
    float m = fmaxf(fmaxf(fabsf(v.x), fabsf(v.y)), fmaxf(fabsf(v.z), fabsf(v.w)));
    #pragma unroll
    for (int off = 32; off >= 1; off >>= 1) m = fmaxf(m, __shfl_down(m, off));
    __shared__ float red[4];
    if ((t & 63) == 0) red[t >> 6] = m;
    __syncthreads();
    float mm = fmaxf(fmaxf(red[0], red[1]), fmaxf(red[2], red[3]));
    mm = fmaxf(mm, EPSF);
    const float s = 127.0f / mm;
    if (t == 0) rs[row] = mm / 127.0f;
    char4 o;
    o.x = (i8)(int)fminf(fmaxf(rintf(v.x * s), -128.f), 127.f);
    o.y = (i8)(int)fminf(fmaxf(rintf(v.y * s), -128.f), 127.f);
    o.z = (i8)(int)fminf(fmaxf(rintf(v.z * s), -128.f), 127.f);
    o.w = (i8)(int)fminf(fmaxf(rintf(v.w * s), -128.f), 127.f);
    ((char4*)(xq + (size_t)row * C))[t] = o;
}

// ---------------- int8 MFMA GEMM: out[M,1024] = A[M,1024] x W[1024,1024]^T ----------------
// 256x256 tile, BK=64, 8 waves (2Mx4N), per-wave 128x64 output.
// 4-deep LDS ring (4 x 32KB = 128KB), stage t+2 while computing t.
// ONE barrier per K-tile: the 4-deep ring means buffer (t+2)&3 was last read
// two barriers ago, so intra-tile barriers are unnecessary -- dropping them
// lets waves desync so one wave's ds_reads overlap another's MFMAs.
// Plain C++ ds_reads (compiler emits fine-grained lgkmcnt; m97 precedent),
// counted vmcnt(4) never drains in main loop, setprio around MFMA cluster.
// LDS XOR-swizzle via inverse-swizzled global source + swizzled ds_read.
// Exact i32 accumulation, numerics unchanged.
template<bool QKV, int NNB>
__global__ __launch_bounds__(512, 2) void gemm_kernel(const i8* __restrict__ A,
    const i8* __restrict__ w8, const float* __restrict__ rs_row,
    const double* __restrict__ wsum, u16* __restrict__ qb, u16* __restrict__ kb,
    u16* __restrict__ vt, float* __restrict__ outp, const float* __restrict__ bias)
{
    constexpr int K = 1024, N = 1024;
    constexpr int NT = 16;                           // K-tiles of 64
    __shared__ __align__(16) i8 Asm[4][256 * 64];    // 64 KiB
    __shared__ __align__(16) i8 Bsm[4][256 * 64];    // 64 KiB

    const int t = threadIdx.x;

    // bijective XCD swizzle (nwg % 8 == 0 for both grids)
    const int nwg = NNB * 64;
    const int wg = (int)blockIdx.x;
    const int swz = (wg & 7) * (nwg >> 3) + (wg >> 3);
    const int mb = swz / NNB, nb = swz % NNB;
    const int m0 = mb * 256;
    const int mat = QKV ? (nb >> 2) : 3;
    const int n0m = QKV ? ((nb & 3) * 256) : (nb * 256);   // col base within mat
    const i8* Bw = w8 + (size_t)mat * 1048576;

    const int lane = t & 63, wv = t >> 6;
    const int wm = wv >> 2, wn = wv & 3;             // 2x4 wave grid
    const int mr = lane & 15, quad = lane >> 4;

    // staging granules: g1=t, g2=t+512 (16B each, linear LDS dest).
    // logical source offset = inverse swizzle of the physical byte address.
    const int g1 = t, g2 = t + 512;
    const int L1 = (g1 * 16) ^ (((g1 >> 3) & 7) << 4);
    const int L2 = (g2 * 16) ^ (((g2 >> 3) & 7) << 4);
    const i8* a1 = A  + (size_t)(m0  + (L1 >> 6)) * K + (L1 & 63);
    const i8* a2 = A  + (size_t)(m0  + (L2 >> 6)) * K + (L2 & 63);
    const i8* b1 = Bw + (size_t)(n0m + (L1 >> 6)) * K + (L1 & 63);
    const i8* b2 = Bw + (size_t)(n0m + (L2 >> 6)) * K + (L2 & 63);

    // swizzled fragment read offsets (vvs constant per thread: rows are 16-aligned)
    const int vvs = (mr >> 1) & 7;
    int aoff[8], boff[4];
    #pragma unroll
    for (int m = 0; m < 8; ++m)
        aoff[m] = ((wm * 128 + m * 16 + mr) * 64 + quad * 16) ^ (vvs << 4);
    #pragma unroll
    for (int n = 0; n < 4; ++n)
        boff[n] = ((wn * 64 + n * 16 + mr) * 64 + quad * 16) ^ (vvs << 4);

    i32x4 acc[8][4];
    #pragma unroll
    for (int m = 0; m < 8; ++m)
        #pragma unroll
        for (int n = 0; n < 4; ++n) acc[m][n] = (i32x4){0, 0, 0, 0};

    // prologue: stage tiles 0 and 1
    #pragma unroll
    for (int p = 0; p < 2; ++p) {
        const int k0 = p * 64;
        __builtin_amdgcn_global_load_lds((const AS1 void*)(a1 + k0), (AS3 void*)&Asm[p][g1 * 16], 16, 0, 0);
        __builtin_amdgcn_global_load_lds((const AS1 void*)(a2 + k0), (AS3 void*)&Asm[p][g2 * 16], 16, 0, 0);
        __builtin_amdgcn_global_load_lds((const AS1 void*)(b1 + k0), (AS3 void*)&Bsm[p][g1 * 16], 16, 0, 0);
        __builtin_amdgcn_global_load_lds((const AS1 void*)(b2 + k0), (AS3 void*)&Bsm[p][g2 * 16], 16, 0, 0);
    }
    asm volatile("s_waitcnt vmcnt(4)" ::: "memory");   // tile 0 landed; tile 1 in flight
    __builtin_amdgcn_s_barrier();
    __builtin_amdgcn_sched_barrier(0);

    for (int tt = 0; tt < NT; ++tt) {
        const i8* Ac = Asm[tt & 3];
        const i8* Bc = Bsm[tt & 3];
        i8* An = Asm[(tt + 2) & 3];
        i8* Bn = Bsm[(tt + 2) & 3];
        const int kn = (tt + 2) * 64;

        // issue next-next tile's staging first (T14 issue-early)
        if (tt < NT - 2) {
            __builtin_amdgcn_global_load_lds((const AS1 void*)(a1 + kn), (AS3 void*)&An[g1 * 16], 16, 0, 0);
            __builtin_amdgcn_global_load_lds((const AS1 void*)(a2 + kn), (AS3 void*)&An[g2 * 16], 16, 0, 0);
            __builtin_amdgcn_global_load_lds((const AS1 void*)(b1 + kn), (AS3 void*)&Bn[g1 * 16], 16, 0, 0);
            __builtin_amdgcn_global_load_lds((const AS1 void*)(b2 + kn), (AS3 void*)&Bn[g2 * 16], 16, 0, 0);
        }

        // fragment reads: plain loads -- compiler interleaves lgkmcnt with MFMAs
        i32x4 af[8], bf[4];
        #pragma unroll
        for (int m = 0; m < 8; ++m) af[m] = *(const i32x4*)&Ac[aoff[m]];
        #pragma unroll
        for (int n = 0; n < 4; ++n) bf[n] = *(const i32x4*)&Bc[boff[n]];

        __builtin_amdgcn_s_setprio(1);
        #pragma unroll
        for (int m = 0; m < 8; ++m)
            #pragma unroll
            for (int n = 0; n < 4; ++n)
                acc[m][n] = __builtin_amdgcn_mfma_i32_16x16x64_i8(af[m], bf[n], acc[m][n], 0, 0, 0);
        __builtin_amdgcn_s_setprio(0);

        // tile boundary: tile t+1 must have landed; keep t+2's 4 loads in flight
        if (tt < NT - 2) {
            asm volatile("s_waitcnt vmcnt(4)" ::: "memory");
        } else if (tt < NT - 1) {
            asm volatile("s_waitcnt vmcnt(0)" ::: "memory");
        }
        __builtin_amdgcn_s_barrier();
        __builtin_amdgcn_sched_barrier(0);
    }

    float wsc = fmaxf((float)(wsum[mat] * (1.0 / 1048576.0)), EPSF);
    if (QKV && mat == 0) wsc *= 0.125f;              // fold 1/sqrt(hd) into q scale

    if (QKV && mat == 2) {
        // V^T store: vt[(b*1024 + col)*256 + tloc], 4 consecutive tokens per ushort4
        #pragma unroll
        for (int m = 0; m < 8; ++m) {
            const int gr0 = m0 + wm * 128 + m * 16 + quad * 4;
            const int bbi = gr0 >> 8, tl = gr0 & 255;
            const float4 rs4 = *(const float4*)(rs_row + gr0);
            #pragma unroll
            for (int n = 0; n < 4; ++n) {
                const int gcol = n0m + wn * 64 + n * 16 + mr;
                ushort4 o;
                o.x = f2bf_rne((float)acc[m][n][0] * rs4.x * wsc);
                o.y = f2bf_rne((float)acc[m][n][1] * rs4.y * wsc);
                o.z = f2bf_rne((float)acc[m][n][2] * rs4.z * wsc);
                o.w = f2bf_rne((float)acc[m][n][3] * rs4.w * wsc);
                *(ushort4*)(vt + (size_t)(bbi * 1024 + gcol) * 256 + tl) = o;
            }
        }
        return;
    }

    u16* ob = QKV ? ((mat == 0) ? qb : kb) : nullptr;
    #pragma unroll
    for (int m = 0; m < 8; ++m) {
        const int gr0 = m0 + wm * 128 + m * 16 + quad * 4;
        #pragma unroll
        for (int r = 0; r < 4; ++r) {
            const int grow = gr0 + r;
            const float sc = rs_row[grow] * wsc;
            #pragma unroll
            for (int n = 0; n < 4; ++n) {
                const int gcol = n0m + wn * 64 + n * 16 + mr;
                const float val = (float)acc[m][n][r] * sc;
                if (QKV) {
                    ob[(size_t)grow * N + gcol] = f2bf_rne(val);
                } else {
                    outp[(size_t)grow * N + gcol] = val + bias[gcol];
                }
            }
        }
    }
}

// ---------------- LDS-free MFMA flash attention ----------------
// block = (b,h,qtile); wave = 16 q-rows. S^T = K Q^T (C layout: row=j, col=q)
// -> softmax reduces over regs+quads (2 shuffles) -> P^T->A-frag via 8
// shuffles + 4 selects per 32-j chunk -> O = P V with V^T B-frags from global.
// r5: r1 body (natural ~60-VGPR allocation, NO min-waves pin: r4's
// launch_bounds(256,8) forced VGPR to 32 and spilled Sp[16] to scratch --
// WRITE_SIZE 65->244 MB, dur 193us) + r2's XCD-co-locating grid remap
// (proven: FETCH 98->49 MB, K/V L2-resident).
__global__ __launch_bounds__(256) void attn_kernel(const u16* __restrict__ qb,
    const u16* __restrict__ kb, const u16* __restrict__ vt, float* __restrict__ y)
{
    const int t = threadIdx.x;
    const int i = (int)blockIdx.x;
    const int qt = 3 - ((i >> 3) & 3);               // heavy qtiles first per bh group
    const int bh = ((i >> 5) << 3) | (i & 7);        // 4 qt-blocks of a bh: same XCD, 8 apart
    const int b = bh >> 4, h = bh & 15;
    const int w = t >> 6, lane = t & 63;
    const int cl = lane & 15, quad = lane >> 4;
    const size_t gb = (size_t)(b * T) * 1024 + h * 64;             // q/k row-major base
    const u16* vtb = vt + (size_t)(b * 1024 + h * 64) * 256;       // V^T base

    const int qrow = qt * 64 + w * 16;
    const int jtiles = (qrow >> 4) + 1;              // causal: j-tiles 0..jtiles-1

    const u16* qrp = qb + gb + (size_t)(qrow + cl) * 1024 + quad * 8;
    bf16x8 qf0 = *(const bf16x8*)qrp;                // B-frag: n=q, k=d
    bf16x8 qf1 = *(const bf16x8*)(qrp + 32);

    f32x4 Sp[16];
    #pragma unroll
    for (int i2 = 0; i2 < 16; ++i2) Sp[i2] = (f32x4){0.f, 0.f, 0.f, 0.f};

    // --- S^T = K Q^T: A-frag m=j (lane cl = j-local), k=d ---
    const u16* krp = kb + gb + (size_t)cl * 1024 + quad * 8;
    #pragma unroll
    for (int jt = 0; jt < 16; ++jt) {
        if (jt < jtiles) {
            const u16* kp = krp + (size_t)(jt * 16) * 1024;
            bf16x8 kf0 = *(const bf16x8*)kp;
            bf16x8 kf1 = *(const bf16x8*)(kp + 32);
            Sp[jt] = __builtin_amdgcn_mfma_f32_16x16x32_bf16(kf0, qf0, Sp[jt], 0, 0, 0);
            Sp[jt] = __builtin_amdgcn_mfma_f32_16x16x32_bf16(kf1, qf1, Sp[jt], 0, 0, 0);
            if (jt == jtiles - 1) {                  // diagonal: mask j > q
                #pragma unroll
                for (int r = 0; r < 4; ++r)
                    if (quad * 4 + r > cl) Sp[jt][r] = -INFINITY;
            }
        }
    }

    // --- softmax over j (regs x quads); q = cl is lane-resident ---
    float mx = -INFINITY;
    #pragma unroll
    for (int jt = 0; jt < 16; ++jt) if (jt < jtiles) {
        #pragma unroll
        for (int r = 0; r < 4; ++r) mx = fmaxf(mx, Sp[jt][r]);
    }
    mx = fmaxf(mx, __shfl_xor(mx, 16));
    mx = fmaxf(mx, __shfl_xor(mx, 32));
    float l = 0.f;
    #pragma unroll
    for (int jt = 0; jt < 16; ++jt) if (jt < jtiles) {
        #pragma unroll
        for (int r = 0; r < 4; ++r) {
            float p = __expf(Sp[jt][r] - mx);
            Sp[jt][r] = p;
            l += p;
        }
    }
    l += __shfl_xor(l, 16);
    l += __shfl_xor(l, 32);

    // --- O = P V: A-frag built in-register from P^T via shuffles ---
    f32x4 O[4];
    #pragma unroll
    for (int i2 = 0; i2 < 4; ++i2) O[i2] = (f32x4){0.f, 0.f, 0.f, 0.f};

    const int s01 = ((quad & 1) << 5) + cl;          // src lane for frag slots 0-3
    const bool lo = quad < 2;                        // dest quads 0,1 use tile 2jc
    #pragma unroll
    for (int jc = 0; jc < 8; ++jc) {
        if (jc * 2 < jtiles) {
            int pk[2][2];                            // [tile][reg-pair] bf16x2
            #pragma unroll
            for (int s = 0; s < 2; ++s) {
                const f32x4 v = Sp[jc * 2 + s];      // tile >= jtiles is all-zero
                pk[s][0] = (int)((unsigned)f2bf_rne(v[0]) | ((unsigned)f2bf_rne(v[1]) << 16));
                pk[s][1] = (int)((unsigned)f2bf_rne(v[2]) | ((unsigned)f2bf_rne(v[3]) << 16));
            }
            int a0 = __shfl(pk[0][0], s01),      a1 = __shfl(pk[0][1], s01);
            int a2 = __shfl(pk[0][0], s01 + 16), a3 = __shfl(pk[0][1], s01 + 16);
            int b0 = __shfl(pk[1][0], s01),      b1 = __shfl(pk[1][1], s01);
            int b2 = __shfl(pk[1][0], s01 + 16), b3 = __shfl(pk[1][1], s01 + 16);
            union { int i[4]; bf16x8 v; } af;
            af.i[0] = lo ? a0 : b0;
            af.i[1] = lo ? a1 : b1;
            af.i[2] = lo ? a2 : b2;
            af.i[3] = lo ? a3 : b3;
            const u16* vp = vtb + (size_t)cl * 256 + jc * 32 + quad * 8;
            #pragma unroll
            for (int dt = 0; dt < 4; ++dt) {
                bf16x8 vf = *(const bf16x8*)(vp + (size_t)dt * 16 * 256);
                O[dt] = __builtin_amdgcn_mfma_f32_16x16x32_bf16(af.v, vf, O[dt], 0, 0, 0);
            }
        }
    }

    // --- normalize + store: O row = q-local = quad*4+r, col = d = dt*16+cl ---
    float inv[4];
    #pragma unroll
    for (int r = 0; r < 4; ++r) inv[r] = 1.0f / __shfl(l, quad * 4 + r);
    #pragma unroll
    for (int dt = 0; dt < 4; ++dt)
        #pragma unroll
        for (int r = 0; r < 4; ++r)
            y[gb + (size_t)(qrow + quad * 4 + r) * 1024 + dt * 16 + cl] = O[dt][r] * inv[r];
}

extern "C" void kernel_launch(void* const* d_in, const int* in_sizes, int n_in,
                              void* d_out, int out_size, void* d_ws, size_t ws_size,
                              hipStream_t stream) {
    (void)in_sizes; (void)n_in; (void)out_size; (void)ws_size;
    const float* x  = (const float*)d_in[0];
    const float* Wq = (const float*)d_in[1];
    const float* Wk = (const float*)d_in[2];
    const float* Wv = (const float*)d_in[3];
    const float* Wp = (const float*)d_in[4];
    const float* bp = (const float*)d_in[5];
    float* out = (float*)d_out;
    char* ws = (char*)d_ws;

    i8*     w8   = (i8*)(ws + W8_OFF);
    i8*     xq8  = (i8*)(ws + XQ8_OFF);
    float*  rsx  = (float*)(ws + RSX_OFF);
    float*  rsy  = (float*)(ws + RSY_OFF);
    double* wsum = (double*)(ws + WSUM_OFF);
    double* wpart= (double*)(ws + WPART_OFF);
    u16*    qb   = (u16*)(ws + QB_OFF);
    u16*    kb   = (u16*)(ws + KB_OFF);
    u16*    vt   = (u16*)(ws + VT_OFF);

    wsum1_kernel<<<256, 256, 0, stream>>>(Wq, Wk, Wv, Wp, wpart);
    wsum2_kernel<<<1, 256, 0, stream>>>(wpart, wsum);
    wquant_kernel<<<4096, 256, 0, stream>>>(Wq, Wk, Wv, Wp, wsum, w8);
    actquant_kernel<<<M, 256, 0, stream>>>(x, xq8, rsx);

    // fused q/k/v: 3 mats x 4 n-blocks (256 cols) x 64 m-blocks, 512 thr, 256^2 tiles
    gemm_kernel<true, 12><<<768, 512, 0, stream>>>(xq8, w8, rsx, wsum, qb, kb, vt, nullptr, nullptr);

    attn_kernel<<<4 * 1024, 256, 0, stream>>>(qb, kb, vt, out);   // y -> d_out (scratch)

    actquant_kernel<<<M, 256, 0, stream>>>(out, xq8, rsy);        // y -> yq8
    gemm_kernel<false, 4><<<256, 512, 0, stream>>>(xq8, w8, rsy, wsum, nullptr, nullptr, nullptr, out, bp);
}

// Round 6
// 319.041 us; speedup vs baseline: 1.3414x; 1.0975x over previous
//
#include <hip/hip_runtime.h>
#include <math.h>

#define AS1 __attribute__((address_space(1)))
#define AS3 __attribute__((address_space(3)))

typedef unsigned short u16;
typedef signed char i8;
typedef short bf16x8 __attribute__((ext_vector_type(8)));
typedef float f32x4 __attribute__((ext_vector_type(4)));
typedef int i32x4 __attribute__((ext_vector_type(4)));

static constexpr int BB = 64, T = 256, C = 1024, H = 16, HD = 64;
static constexpr int M = BB * T;          // 16384 token rows
static constexpr float EPSF = 1e-5f;

// ---- workspace layout (bytes) ----
static constexpr size_t W8_OFF   = 0;                    // 4 x 1M i8 = 4 MiB frag-packed ternary weights
static constexpr size_t XQ8_OFF  = 4ull  << 20;          // 16M i8 = 16 MiB (reused for yq)
static constexpr size_t RSX_OFF  = 20ull << 20;          // 16384 f32
static constexpr size_t RSY_OFF  = (20ull << 20) + (64 << 10);
static constexpr size_t WSUM_OFF = (20ull << 20) + (128 << 10);   // 4 f64
static constexpr size_t WPART_OFF= WSUM_OFF + 64;                 // 256 f64
static constexpr size_t QB_OFF   = 21ull << 20;          // 32 MiB bf16
static constexpr size_t KB_OFF   = 53ull << 20;          // 32 MiB bf16
static constexpr size_t VT_OFF   = 85ull << 20;          // 32 MiB bf16 V^T [b][h*64+d][tloc]

// round-to-nearest-even f32 -> bf16 bits (finite inputs)
__device__ __forceinline__ u16 f2bf_rne(float f) {
    unsigned x = __float_as_uint(f);
    unsigned r = x + 0x7FFF + ((x >> 16) & 1);
    return (u16)(r >> 16);
}

// ---------------- weight |w| sum, stage 1 (deterministic, f64) ----------------
__global__ __launch_bounds__(256) void wsum1_kernel(const float* __restrict__ Wq,
    const float* __restrict__ Wk, const float* __restrict__ Wv,
    const float* __restrict__ Wp, double* __restrict__ wpart)
{
    const int mat = blockIdx.x >> 6;
    const float* W = (mat == 0) ? Wq : (mat == 1) ? Wk : (mat == 2) ? Wv : Wp;
    const int t = threadIdx.x;
    const int base = (blockIdx.x & 63) * 256 + t;
    double s = 0.0;
    for (int i = 0; i < 64; ++i) s += (double)fabsf(W[base + (i << 14)]);
    #pragma unroll
    for (int off = 32; off >= 1; off >>= 1) s += __shfl_down(s, off);
    __shared__ double red[4];
    if ((t & 63) == 0) red[t >> 6] = s;
    __syncthreads();
    if (t == 0) wpart[blockIdx.x] = red[0] + red[1] + red[2] + red[3];
}

__global__ __launch_bounds__(256) void wsum2_kernel(const double* __restrict__ wpart,
                                                    double* __restrict__ wsum)
{
    const int t = threadIdx.x;
    double s = wpart[t];
    #pragma unroll
    for (int off = 32; off >= 1; off >>= 1) s += __shfl_down(s, off);
    if ((t & 63) == 0) wsum[t >> 6] = s;
}

// ---------------- ternary weight quantization -> frag-packed int8 ----------------
// Packed layout (16B granules): granule g = (nt*16 + kt)*64 + lane holds
// W[nt*16 + (lane&15)][kt*64 + (lane>>4)*16 .. +15], so a wave's MFMA B-frag
// bf[n] at k-tile kt is ONE fully coalesced 1KB global_load_dwordx4 -- B never
// touches LDS in the GEMM (r5 PMC: 128KB LDS ring -> 1 block/CU, LDS-BW bound).
__global__ __launch_bounds__(256) void wquant_kernel(const float* __restrict__ Wq,
    const float* __restrict__ Wk, const float* __restrict__ Wv,
    const float* __restrict__ Wp, const double* __restrict__ wsum,
    i8* __restrict__ w8)
{
    const int mat = blockIdx.x >> 8;
    const float* W = (mat == 0) ? Wq : (mat == 1) ? Wk : (mat == 2) ? Wv : Wp;
    const float mean = (float)(wsum[mat] * (1.0 / 1048576.0));
    const float s = 1.0f / fmaxf(mean, EPSF);
    const int g = (blockIdx.x & 255) * 256 + threadIdx.x;   // granule 0..65535
    const int lane = g & 63, kt = (g >> 6) & 15, nt = g >> 10;
    const int row = nt * 16 + (lane & 15);
    const int k0 = kt * 64 + (lane >> 4) * 16;
    const float* src = W + (size_t)row * 1024 + k0;
    union { i8 b[16]; i32x4 v; } o;
    #pragma unroll
    for (int j = 0; j < 16; ++j)
        o.b[j] = (i8)(int)fminf(fmaxf(rintf(src[j] * s), -1.f), 1.f);
    *(i32x4*)(w8 + ((size_t)mat << 20) + (size_t)g * 16) = o.v;
}

// ---------------- per-token activation quantization -> int8 ----------------
__global__ __launch_bounds__(256) void actquant_kernel(const float* __restrict__ x,
    i8* __restrict__ xq, float* __restrict__ rs)
{
    const int row = blockIdx.x;
    const int t = threadIdx.x;
    float4 v = ((const float4*)(x + (size_t)row * C))[t];
    float m = fmaxf(fmaxf(fabsf(v.x), fabsf(v.y)), fmaxf(fabsf(v.z), fabsf(v.w)));
    #pragma unroll
    for (int off = 32; off >= 1; off >>= 1) m = fmaxf(m, __shfl_down(m, off));
    __shared__ float red[4];
    if ((t & 63) == 0) red[t >> 6] = m;
    __syncthreads();
    float mm = fmaxf(fmaxf(red[0], red[1]), fmaxf(red[2], red[3]));
    mm = fmaxf(mm, EPSF);
    const float s = 127.0f / mm;
    if (t == 0) rs[row] = mm / 127.0f;
    char4 o;
    o.x = (i8)(int)fminf(fmaxf(rintf(v.x * s), -128.f), 127.f);
    o.y = (i8)(int)fminf(fmaxf(rintf(v.y * s), -128.f), 127.f);
    o.z = (i8)(int)fminf(fmaxf(rintf(v.z * s), -128.f), 127.f);
    o.w = (i8)(int)fminf(fmaxf(rintf(v.w * s), -128.f), 127.f);
    ((char4*)(xq + (size_t)row * C))[t] = o;
}

// ---------------- int8 MFMA GEMM: out[M,1024] = A[M,1024] x W[1024,1024]^T ----------------
// 256x256 tile, BK=64, 8 waves (2Mx4N), per-wave 128x64 output.
// A: 4-deep LDS ring, A-ONLY (4 x 16KB = 64KB -> 2 blocks/CU; r5 had B in LDS
// too = 128KB -> 1 block/CU, LDS-bandwidth bound at MfmaUtil 24%).
// B: direct from L2 via frag-packed w8 (see wquant) -- 4 coalesced 1KB loads
// per wave per K-tile, no LDS, no staging. bf loads issue BEFORE the A-stage
// so the compiler's implicit bf-wait (vmcnt(2)) leaves staging in flight;
// in-order VMEM retirement makes the bf-wait also prove stage(t+1) landed.
// One barrier per K-tile; boundary s_waitcnt vmcnt(2) never drains.
// Exact i32 accumulation, numerics unchanged.
template<bool QKV, int NNB>
__global__ __launch_bounds__(512, 2) void gemm_kernel(const i8* __restrict__ A,
    const i8* __restrict__ w8, const float* __restrict__ rs_row,
    const double* __restrict__ wsum, u16* __restrict__ qb, u16* __restrict__ kb,
    u16* __restrict__ vt, float* __restrict__ outp, const float* __restrict__ bias)
{
    constexpr int K = 1024, N = 1024;
    constexpr int NT = 16;                           // K-tiles of 64
    __shared__ __align__(16) i8 Asm[4][256 * 64];    // 64 KiB total

    const int t = threadIdx.x;

    // bijective XCD swizzle (nwg % 8 == 0 for both grids)
    const int nwg = NNB * 64;
    const int wg = (int)blockIdx.x;
    const int swz = (wg & 7) * (nwg >> 3) + (wg >> 3);
    const int mb = swz / NNB, nb = swz % NNB;
    const int m0 = mb * 256;
    const int mat = QKV ? (nb >> 2) : 3;
    const int n0m = QKV ? ((nb & 3) * 256) : (nb * 256);   // col base within mat
    const i8* Bw = w8 + ((size_t)mat << 20);               // frag-packed weights

    const int lane = t & 63, wv = t >> 6;
    const int wm = wv >> 2, wn = wv & 3;             // 2x4 wave grid
    const int mr = lane & 15, quad = lane >> 4;

    // A staging granules: g1=t, g2=t+512 (16B each, linear LDS dest).
    // logical source offset = inverse swizzle of the physical byte address.
    const int g1 = t, g2 = t + 512;
    const int L1 = (g1 * 16) ^ (((g1 >> 3) & 7) << 4);
    const int L2 = (g2 * 16) ^ (((g2 >> 3) & 7) << 4);
    const i8* a1 = A + (size_t)(m0 + (L1 >> 6)) * K + (L1 & 63);
    const i8* a2 = A + (size_t)(m0 + (L2 >> 6)) * K + (L2 & 63);

    // swizzled A fragment read offsets
    const int vvs = (mr >> 1) & 7;
    int aoff[8];
    #pragma unroll
    for (int m = 0; m < 8; ++m)
        aoff[m] = ((wm * 128 + m * 16 + mr) * 64 + quad * 16) ^ (vvs << 4);

    // B frag base: granule ((nt*16+kt)*64+lane)*16
    const int ntb = (n0m >> 4) + wn * 4;
    const i8* bfp = Bw + (size_t)ntb * 16384 + (size_t)lane * 16;

    i32x4 acc[8][4];
    #pragma unroll
    for (int m = 0; m < 8; ++m)
        #pragma unroll
        for (int n = 0; n < 4; ++n) acc[m][n] = (i32x4){0, 0, 0, 0};

    // prologue: stage A tiles 0 and 1
    #pragma unroll
    for (int p = 0; p < 2; ++p) {
        const int k0 = p * 64;
        __builtin_amdgcn_global_load_lds((const AS1 void*)(a1 + k0), (AS3 void*)&Asm[p][g1 * 16], 16, 0, 0);
        __builtin_amdgcn_global_load_lds((const AS1 void*)(a2 + k0), (AS3 void*)&Asm[p][g2 * 16], 16, 0, 0);
    }
    asm volatile("s_waitcnt vmcnt(2)" ::: "memory");   // tile 0 landed; tile 1 in flight
    __builtin_amdgcn_s_barrier();
    __builtin_amdgcn_sched_barrier(0);

    for (int tt = 0; tt < NT; ++tt) {
        const i8* Ac = Asm[tt & 3];
        i8* An = Asm[(tt + 2) & 3];
        const int kn = (tt + 2) * 64;

        // B frags for this tile, straight from L2 (issued before the A-stage)
        i32x4 bf[4];
        #pragma unroll
        for (int n = 0; n < 4; ++n)
            bf[n] = *(const i32x4*)(bfp + (size_t)n * 16384 + tt * 1024);

        // stage A(t+2) into the ring
        if (tt < NT - 2) {
            __builtin_amdgcn_global_load_lds((const AS1 void*)(a1 + kn), (AS3 void*)&An[g1 * 16], 16, 0, 0);
            __builtin_amdgcn_global_load_lds((const AS1 void*)(a2 + kn), (AS3 void*)&An[g2 * 16], 16, 0, 0);
        }

        // A fragment reads from LDS
        i32x4 af[8];
        #pragma unroll
        for (int m = 0; m < 8; ++m) af[m] = *(const i32x4*)&Ac[aoff[m]];

        __builtin_amdgcn_s_setprio(1);
        #pragma unroll
        for (int m = 0; m < 8; ++m)
            #pragma unroll
            for (int n = 0; n < 4; ++n)
                acc[m][n] = __builtin_amdgcn_mfma_i32_16x16x64_i8(af[m], bf[n], acc[m][n], 0, 0, 0);
        __builtin_amdgcn_s_setprio(0);

        // tile boundary: stage(t+1) proven done via in-order retirement;
        // keep stage(t+2)'s 2 loads in flight
        if (tt < NT - 2) {
            asm volatile("s_waitcnt vmcnt(2)" ::: "memory");
        } else if (tt < NT - 1) {
            asm volatile("s_waitcnt vmcnt(0)" ::: "memory");
        }
        __builtin_amdgcn_s_barrier();
        __builtin_amdgcn_sched_barrier(0);
    }

    float wsc = fmaxf((float)(wsum[mat] * (1.0 / 1048576.0)), EPSF);
    if (QKV && mat == 0) wsc *= 0.125f;              // fold 1/sqrt(hd) into q scale

    if (QKV && mat == 2) {
        // V^T store: vt[(b*1024 + col)*256 + tloc], 4 consecutive tokens per ushort4
        #pragma unroll
        for (int m = 0; m < 8; ++m) {
            const int gr0 = m0 + wm * 128 + m * 16 + quad * 4;
            const int bbi = gr0 >> 8, tl = gr0 & 255;
            const float4 rs4 = *(const float4*)(rs_row + gr0);
            #pragma unroll
            for (int n = 0; n < 4; ++n) {
                const int gcol = n0m + wn * 64 + n * 16 + mr;
                ushort4 o;
                o.x = f2bf_rne((float)acc[m][n][0] * rs4.x * wsc);
                o.y = f2bf_rne((float)acc[m][n][1] * rs4.y * wsc);
                o.z = f2bf_rne((float)acc[m][n][2] * rs4.z * wsc);
                o.w = f2bf_rne((float)acc[m][n][3] * rs4.w * wsc);
                *(ushort4*)(vt + (size_t)(bbi * 1024 + gcol) * 256 + tl) = o;
            }
        }
        return;
    }

    u16* ob = QKV ? ((mat == 0) ? qb : kb) : nullptr;
    #pragma unroll
    for (int m = 0; m < 8; ++m) {
        const int gr0 = m0 + wm * 128 + m * 16 + quad * 4;
        #pragma unroll
        for (int r = 0; r < 4; ++r) {
            const int grow = gr0 + r;
            const float sc = rs_row[grow] * wsc;
            #pragma unroll
            for (int n = 0; n < 4; ++n) {
                const int gcol = n0m + wn * 64 + n * 16 + mr;
                const float val = (float)acc[m][n][r] * sc;
                if (QKV) {
                    ob[(size_t)grow * N + gcol] = f2bf_rne(val);
                } else {
                    outp[(size_t)grow * N + gcol] = val + bias[gcol];
                }
            }
        }
    }
}

// ---------------- LDS-free MFMA flash attention ----------------
// block = (b,h,qtile); wave = 16 q-rows. S^T = K Q^T (C layout: row=j, col=q)
// -> softmax reduces over regs+quads (2 shuffles) -> P^T->A-frag via 8
// shuffles + 4 selects per 32-j chunk -> O = P V with V^T B-frags from global.
// r6: exact r1 grid order (qt-major, heavy qtiles dispatch FIRST = LPT
// scheduling). r5 proved the interleaved remap's tail (heavy blocks dispatched
// last) cost ~36us while L2-locality (FETCH 98->49MB) bought ~nothing --
// r2 (16% occ) and r5 (25% occ) both sat at ~117us vs r1's 81us.
__global__ __launch_bounds__(256) void attn_kernel(const u16* __restrict__ qb,
    const u16* __restrict__ kb, const u16* __restrict__ vt, float* __restrict__ y)
{
    const int t = threadIdx.x;
    const int qt = 3 - (int)(blockIdx.x >> 10);      // heavy qtiles dispatch first
    const int bh = blockIdx.x & 1023;
    const int b = bh >> 4, h = bh & 15;
    const int w = t >> 6, lane = t & 63;
    const int cl = lane & 15, quad = lane >> 4;
    const size_t gb = (size_t)(b * T) * 1024 + h * 64;             // q/k row-major base
    const u16* vtb = vt + (size_t)(b * 1024 + h * 64) * 256;       // V^T base

    const int qrow = qt * 64 + w * 16;
    const int jtiles = (qrow >> 4) + 1;              // causal: j-tiles 0..jtiles-1

    const u16* qrp = qb + gb + (size_t)(qrow + cl) * 1024 + quad * 8;
    bf16x8 qf0 = *(const bf16x8*)qrp;                // B-frag: n=q, k=d
    bf16x8 qf1 = *(const bf16x8*)(qrp + 32);

    f32x4 Sp[16];
    #pragma unroll
    for (int i2 = 0; i2 < 16; ++i2) Sp[i2] = (f32x4){0.f, 0.f, 0.f, 0.f};

    // --- S^T = K Q^T: A-frag m=j (lane cl = j-local), k=d ---
    const u16* krp = kb + gb + (size_t)cl * 1024 + quad * 8;
    #pragma unroll
    for (int jt = 0; jt < 16; ++jt) {
        if (jt < jtiles) {
            const u16* kp = krp + (size_t)(jt * 16) * 1024;
            bf16x8 kf0 = *(const bf16x8*)kp;
            bf16x8 kf1 = *(const bf16x8*)(kp + 32);
            Sp[jt] = __builtin_amdgcn_mfma_f32_16x16x32_bf16(kf0, qf0, Sp[jt], 0, 0, 0);
            Sp[jt] = __builtin_amdgcn_mfma_f32_16x16x32_bf16(kf1, qf1, Sp[jt], 0, 0, 0);
            if (jt == jtiles - 1) {                  // diagonal: mask j > q
                #pragma unroll
                for (int r = 0; r < 4; ++r)
                    if (quad * 4 + r > cl) Sp[jt][r] = -INFINITY;
            }
        }
    }

    // --- softmax over j (regs x quads); q = cl is lane-resident ---
    float mx = -INFINITY;
    #pragma unroll
    for (int jt = 0; jt < 16; ++jt) if (jt < jtiles) {
        #pragma unroll
        for (int r = 0; r < 4; ++r) mx = fmaxf(mx, Sp[jt][r]);
    }
    mx = fmaxf(mx, __shfl_xor(mx, 16));
    mx = fmaxf(mx, __shfl_xor(mx, 32));
    float l = 0.f;
    #pragma unroll
    for (int jt = 0; jt < 16; ++jt) if (jt < jtiles) {
        #pragma unroll
        for (int r = 0; r < 4; ++r) {
            float p = __expf(Sp[jt][r] - mx);
            Sp[jt][r] = p;
            l += p;
        }
    }
    l += __shfl_xor(l, 16);
    l += __shfl_xor(l, 32);

    // --- O = P V: A-frag built in-register from P^T via shuffles ---
    f32x4 O[4];
    #pragma unroll
    for (int i2 = 0; i2 < 4; ++i2) O[i2] = (f32x4){0.f, 0.f, 0.f, 0.f};

    const int s01 = ((quad & 1) << 5) + cl;          // src lane for frag slots 0-3
    const bool lo = quad < 2;                        // dest quads 0,1 use tile 2jc
    #pragma unroll
    for (int jc = 0; jc < 8; ++jc) {
        if (jc * 2 < jtiles) {
            int pk[2][2];                            // [tile][reg-pair] bf16x2
            #pragma unroll
            for (int s = 0; s < 2; ++s) {
                const f32x4 v = Sp[jc * 2 + s];      // tile >= jtiles is all-zero
                pk[s][0] = (int)((unsigned)f2bf_rne(v[0]) | ((unsigned)f2bf_rne(v[1]) << 16));
                pk[s][1] = (int)((unsigned)f2bf_rne(v[2]) | ((unsigned)f2bf_rne(v[3]) << 16));
            }
            int a0 = __shfl(pk[0][0], s01),      a1 = __shfl(pk[0][1], s01);
            int a2 = __shfl(pk[0][0], s01 + 16), a3 = __shfl(pk[0][1], s01 + 16);
            int b0 = __shfl(pk[1][0], s01),      b1 = __shfl(pk[1][1], s01);
            int b2 = __shfl(pk[1][0], s01 + 16), b3 = __shfl(pk[1][1], s01 + 16);
            union { int i[4]; bf16x8 v; } af;
            af.i[0] = lo ? a0 : b0;
            af.i[1] = lo ? a1 : b1;
            af.i[2] = lo ? a2 : b2;
            af.i[3] = lo ? a3 : b3;
            const u16* vp = vtb + (size_t)cl * 256 + jc * 32 + quad * 8;
            #pragma unroll
            for (int dt = 0; dt < 4; ++dt) {
                bf16x8 vf = *(const bf16x8*)(vp + (size_t)dt * 16 * 256);
                O[dt] = __builtin_amdgcn_mfma_f32_16x16x32_bf16(af.v, vf, O[dt], 0, 0, 0);
            }
        }
    }

    // --- normalize + store: O row = q-local = quad*4+r, col = d = dt*16+cl ---
    float inv[4];
    #pragma unroll
    for (int r = 0; r < 4; ++r) inv[r] = 1.0f / __shfl(l, quad * 4 + r);
    #pragma unroll
    for (int dt = 0; dt < 4; ++dt)
        #pragma unroll
        for (int r = 0; r < 4; ++r)
            y[gb + (size_t)(qrow + quad * 4 + r) * 1024 + dt * 16 + cl] = O[dt][r] * inv[r];
}

extern "C" void kernel_launch(void* const* d_in, const int* in_sizes, int n_in,
                              void* d_out, int out_size, void* d_ws, size_t ws_size,
                              hipStream_t stream) {
    (void)in_sizes; (void)n_in; (void)out_size; (void)ws_size;
    const float* x  = (const float*)d_in[0];
    const float* Wq = (const float*)d_in[1];
    const float* Wk = (const float*)d_in[2];
    const float* Wv = (const float*)d_in[3];
    const float* Wp = (const float*)d_in[4];
    const float* bp = (const float*)d_in[5];
    float* out = (float*)d_out;
    char* ws = (char*)d_ws;

    i8*     w8   = (i8*)(ws + W8_OFF);
    i8*     xq8  = (i8*)(ws + XQ8_OFF);
    float*  rsx  = (float*)(ws + RSX_OFF);
    float*  rsy  = (float*)(ws + RSY_OFF);
    double* wsum = (double*)(ws + WSUM_OFF);
    double* wpart= (double*)(ws + WPART_OFF);
    u16*    qb   = (u16*)(ws + QB_OFF);
    u16*    kb   = (u16*)(ws + KB_OFF);
    u16*    vt   = (u16*)(ws + VT_OFF);

    wsum1_kernel<<<256, 256, 0, stream>>>(Wq, Wk, Wv, Wp, wpart);
    wsum2_kernel<<<1, 256, 0, stream>>>(wpart, wsum);
    wquant_kernel<<<1024, 256, 0, stream>>>(Wq, Wk, Wv, Wp, wsum, w8);
    actquant_kernel<<<M, 256, 0, stream>>>(x, xq8, rsx);

    // fused q/k/v: 3 mats x 4 n-blocks (256 cols) x 64 m-blocks, 512 thr, 256^2 tiles
    gemm_kernel<true, 12><<<768, 512, 0, stream>>>(xq8, w8, rsx, wsum, qb, kb, vt, nullptr, nullptr);

    attn_kernel<<<4 * 1024, 256, 0, stream>>>(qb, kb, vt, out);   // y -> d_out (scratch)

    actquant_kernel<<<M, 256, 0, stream>>>(out, xq8, rsy);        // y -> yq8
    gemm_kernel<false, 4><<<256, 512, 0, stream>>>(xq8, w8, rsy, wsum, nullptr, nullptr, nullptr, out, bp);
}

// Round 7
// 307.334 us; speedup vs baseline: 1.3925x; 1.0381x over previous
//
#include <hip/hip_runtime.h>
#include <math.h>

#define AS1 __attribute__((address_space(1)))
#define AS3 __attribute__((address_space(3)))

typedef unsigned short u16;
typedef signed char i8;
typedef short bf16x8 __attribute__((ext_vector_type(8)));
typedef float f32x4 __attribute__((ext_vector_type(4)));
typedef int i32x4 __attribute__((ext_vector_type(4)));

static constexpr int BB = 64, T = 256, C = 1024, H = 16, HD = 64;
static constexpr int M = BB * T;          // 16384 token rows
static constexpr float EPSF = 1e-5f;

// ---- workspace layout (bytes) ----
static constexpr size_t W8_OFF   = 0;                    // 4 x 1M i8 = 4 MiB frag-packed ternary weights
static constexpr size_t XQ8_OFF  = 4ull  << 20;          // 16M i8 = 16 MiB (reused for yq)
static constexpr size_t RSX_OFF  = 20ull << 20;          // 16384 f32
static constexpr size_t RSY_OFF  = (20ull << 20) + (64 << 10);
static constexpr size_t WSUM_OFF = (20ull << 20) + (128 << 10);   // 4 f64
static constexpr size_t WPART_OFF= WSUM_OFF + 64;                 // 256 f64
static constexpr size_t QB_OFF   = 21ull << 20;          // 32 MiB bf16
static constexpr size_t KB_OFF   = 53ull << 20;          // 32 MiB bf16
static constexpr size_t VT_OFF   = 85ull << 20;          // 32 MiB bf16 V^T [b][h*64+d][tloc]

// round-to-nearest-even f32 -> bf16 bits (finite inputs)
__device__ __forceinline__ u16 f2bf_rne(float f) {
    unsigned x = __float_as_uint(f);
    unsigned r = x + 0x7FFF + ((x >> 16) & 1);
    return (u16)(r >> 16);
}

// ---------------- weight |w| sum, stage 1 (deterministic, f64) ----------------
__global__ __launch_bounds__(256) void wsum1_kernel(const float* __restrict__ Wq,
    const float* __restrict__ Wk, const float* __restrict__ Wv,
    const float* __restrict__ Wp, double* __restrict__ wpart)
{
    const int mat = blockIdx.x >> 6;
    const float* W = (mat == 0) ? Wq : (mat == 1) ? Wk : (mat == 2) ? Wv : Wp;
    const int t = threadIdx.x;
    const int base = (blockIdx.x & 63) * 256 + t;
    double s = 0.0;
    for (int i = 0; i < 64; ++i) s += (double)fabsf(W[base + (i << 14)]);
    #pragma unroll
    for (int off = 32; off >= 1; off >>= 1) s += __shfl_down(s, off);
    __shared__ double red[4];
    if ((t & 63) == 0) red[t >> 6] = s;
    __syncthreads();
    if (t == 0) wpart[blockIdx.x] = red[0] + red[1] + red[2] + red[3];
}

__global__ __launch_bounds__(256) void wsum2_kernel(const double* __restrict__ wpart,
                                                    double* __restrict__ wsum)
{
    const int t = threadIdx.x;
    double s = wpart[t];
    #pragma unroll
    for (int off = 32; off >= 1; off >>= 1) s += __shfl_down(s, off);
    if ((t & 63) == 0) wsum[t >> 6] = s;
}

// ---------------- ternary weight quantization -> frag-packed int8 ----------------
// Packed layout (16B granules): granule g = (nt*16 + kt)*64 + lane holds
// W[nt*16 + (lane&15)][kt*64 + (lane>>4)*16 .. +15], so a wave's MFMA B-frag
// bf[n] at k-tile kt is ONE fully coalesced 1KB global_load_dwordx4 -- B never
// touches LDS in the GEMM.
__global__ __launch_bounds__(256) void wquant_kernel(const float* __restrict__ Wq,
    const float* __restrict__ Wk, const float* __restrict__ Wv,
    const float* __restrict__ Wp, const double* __restrict__ wsum,
    i8* __restrict__ w8)
{
    const int mat = blockIdx.x >> 8;
    const float* W = (mat == 0) ? Wq : (mat == 1) ? Wk : (mat == 2) ? Wv : Wp;
    const float mean = (float)(wsum[mat] * (1.0 / 1048576.0));
    const float s = 1.0f / fmaxf(mean, EPSF);
    const int g = (blockIdx.x & 255) * 256 + threadIdx.x;   // granule 0..65535
    const int lane = g & 63, kt = (g >> 6) & 15, nt = g >> 10;
    const int row = nt * 16 + (lane & 15);
    const int k0 = kt * 64 + (lane >> 4) * 16;
    const float* src = W + (size_t)row * 1024 + k0;
    union { i8 b[16]; i32x4 v; } o;
    #pragma unroll
    for (int j = 0; j < 16; ++j)
        o.b[j] = (i8)(int)fminf(fmaxf(rintf(src[j] * s), -1.f), 1.f);
    *(i32x4*)(w8 + ((size_t)mat << 20) + (size_t)g * 16) = o.v;
}

// ---------------- per-token activation quantization -> int8 ----------------
__global__ __launch_bounds__(256) void actquant_kernel(const float* __restrict__ x,
    i8* __restrict__ xq, float* __restrict__ rs)
{
    const int row = blockIdx.x;
    const int t = threadIdx.x;
    float4 v = ((const float4*)(x + (size_t)row * C))[t];
    float m = fmaxf(fmaxf(fabsf(v.x), fabsf(v.y)), fmaxf(fabsf(v.z), fabsf(v.w)));
    #pragma unroll
    for (int off = 32; off >= 1; off >>= 1) m = fmaxf(m, __shfl_down(m, off));
    __shared__ float red[4];
    if ((t & 63) == 0) red[t >> 6] = m;
    __syncthreads();
    float mm = fmaxf(fmaxf(red[0], red[1]), fmaxf(red[2], red[3]));
    mm = fmaxf(mm, EPSF);
    const float s = 127.0f / mm;
    if (t == 0) rs[row] = mm / 127.0f;
    char4 o;
    o.x = (i8)(int)fminf(fmaxf(rintf(v.x * s), -128.f), 127.f);
    o.y = (i8)(int)fminf(fmaxf(rintf(v.y * s), -128.f), 127.f);
    o.z = (i8)(int)fminf(fmaxf(rintf(v.z * s), -128.f), 127.f);
    o.w = (i8)(int)fminf(fmaxf(rintf(v.w * s), -128.f), 127.f);
    ((char4*)(xq + (size_t)row * C))[t] = o;
}

// ---------------- int8 MFMA GEMM: out[M,1024] = A[M,1024] x W[1024,1024]^T ----------------
// r7: tile 128x256, 4 waves (256 thr, 1Mx4N), per-wave 128x64 output (acc
// unchanged at 128 AGPRs). Rationale: r6 PMC showed 120 arch-VGPR + 128 AGPR
// = 248 regs/wave on the UNIFIED gfx950 file -> 2 waves/SIMD -> the 8-wave
// 256x256 block was the only block on the CU, so every s_barrier drained the
// whole CU (MfmaUtil stuck at 26% across r5/r6 despite LDS halving). With
// 4-wave blocks, TWO independent blocks co-reside (2 x 32KB LDS, 2 x 4 x 248
// regs): one block's MFMAs cover the other's barrier/load phase.
// A: 4-deep LDS ring (4 x 8KB), XOR-swizzled via inverse-swizzled global src.
// B: direct from L2 via frag-packed w8, 4 x 1KB coalesced loads per tile,
// issued BEFORE the A-stage so in-order retirement makes the compiler's
// implicit bf-wait also prove stage(t+1) landed; boundary vmcnt(2).
// Exact i32 accumulation, numerics unchanged.
template<bool QKV, int NNB>
__global__ __launch_bounds__(256, 2) void gemm_kernel(const i8* __restrict__ A,
    const i8* __restrict__ w8, const float* __restrict__ rs_row,
    const double* __restrict__ wsum, u16* __restrict__ qb, u16* __restrict__ kb,
    u16* __restrict__ vt, float* __restrict__ outp, const float* __restrict__ bias)
{
    constexpr int K = 1024, N = 1024;
    constexpr int NT = 16;                           // K-tiles of 64
    __shared__ __align__(16) i8 Asm[4][128 * 64];    // 32 KiB total

    const int t = threadIdx.x;

    // bijective XCD swizzle (nwg % 8 == 0 for both grids)
    const int nwg = NNB * 128;
    const int wg = (int)blockIdx.x;
    const int swz = (wg & 7) * (nwg >> 3) + (wg >> 3);
    const int mb = swz / NNB, nb = swz % NNB;
    const int m0 = mb * 128;
    const int mat = QKV ? (nb >> 2) : 3;
    const int n0m = QKV ? ((nb & 3) * 256) : (nb * 256);   // col base within mat
    const i8* Bw = w8 + ((size_t)mat << 20);               // frag-packed weights

    const int lane = t & 63, wn = t >> 6;            // 4 waves, 1x4 grid
    const int mr = lane & 15, quad = lane >> 4;

    // A staging granules: g1=t, g2=t+256 (16B each, linear LDS dest).
    // logical source offset = inverse swizzle of the physical byte address.
    const int g1 = t, g2 = t + 256;
    const int L1 = (g1 * 16) ^ (((g1 >> 3) & 7) << 4);
    const int L2 = (g2 * 16) ^ (((g2 >> 3) & 7) << 4);
    const i8* a1 = A + (size_t)(m0 + (L1 >> 6)) * K + (L1 & 63);
    const i8* a2 = A + (size_t)(m0 + (L2 >> 6)) * K + (L2 & 63);

    // swizzled A fragment read offsets
    const int vvs = (mr >> 1) & 7;
    int aoff[8];
    #pragma unroll
    for (int m = 0; m < 8; ++m)
        aoff[m] = ((m * 16 + mr) * 64 + quad * 16) ^ (vvs << 4);

    // B frag base: granule ((nt*16+kt)*64+lane)*16
    const int ntb = (n0m >> 4) + wn * 4;
    const i8* bfp = Bw + (size_t)ntb * 16384 + (size_t)lane * 16;

    i32x4 acc[8][4];
    #pragma unroll
    for (int m = 0; m < 8; ++m)
        #pragma unroll
        for (int n = 0; n < 4; ++n) acc[m][n] = (i32x4){0, 0, 0, 0};

    // prologue: stage A tiles 0 and 1
    #pragma unroll
    for (int p = 0; p < 2; ++p) {
        const int k0 = p * 64;
        __builtin_amdgcn_global_load_lds((const AS1 void*)(a1 + k0), (AS3 void*)&Asm[p][g1 * 16], 16, 0, 0);
        __builtin_amdgcn_global_load_lds((const AS1 void*)(a2 + k0), (AS3 void*)&Asm[p][g2 * 16], 16, 0, 0);
    }
    asm volatile("s_waitcnt vmcnt(2)" ::: "memory");   // tile 0 landed; tile 1 in flight
    __builtin_amdgcn_s_barrier();
    __builtin_amdgcn_sched_barrier(0);

    for (int tt = 0; tt < NT; ++tt) {
        const i8* Ac = Asm[tt & 3];
        i8* An = Asm[(tt + 2) & 3];
        const int kn = (tt + 2) * 64;

        // B frags for this tile, straight from L2 (issued before the A-stage)
        i32x4 bf[4];
        #pragma unroll
        for (int n = 0; n < 4; ++n)
            bf[n] = *(const i32x4*)(bfp + (size_t)n * 16384 + tt * 1024);

        // stage A(t+2) into the ring
        if (tt < NT - 2) {
            __builtin_amdgcn_global_load_lds((const AS1 void*)(a1 + kn), (AS3 void*)&An[g1 * 16], 16, 0, 0);
            __builtin_amdgcn_global_load_lds((const AS1 void*)(a2 + kn), (AS3 void*)&An[g2 * 16], 16, 0, 0);
        }

        // A fragment reads from LDS
        i32x4 af[8];
        #pragma unroll
        for (int m = 0; m < 8; ++m) af[m] = *(const i32x4*)&Ac[aoff[m]];

        __builtin_amdgcn_s_setprio(1);
        #pragma unroll
        for (int m = 0; m < 8; ++m)
            #pragma unroll
            for (int n = 0; n < 4; ++n)
                acc[m][n] = __builtin_amdgcn_mfma_i32_16x16x64_i8(af[m], bf[n], acc[m][n], 0, 0, 0);
        __builtin_amdgcn_s_setprio(0);

        // tile boundary: stage(t+1) proven done via in-order retirement;
        // keep stage(t+2)'s 2 loads in flight
        if (tt < NT - 2) {
            asm volatile("s_waitcnt vmcnt(2)" ::: "memory");
        } else if (tt < NT - 1) {
            asm volatile("s_waitcnt vmcnt(0)" ::: "memory");
        }
        __builtin_amdgcn_s_barrier();
        __builtin_amdgcn_sched_barrier(0);
    }

    float wsc = fmaxf((float)(wsum[mat] * (1.0 / 1048576.0)), EPSF);
    if (QKV && mat == 0) wsc *= 0.125f;              // fold 1/sqrt(hd) into q scale

    if (QKV && mat == 2) {
        // V^T store: vt[(b*1024 + col)*256 + tloc], 4 consecutive tokens per ushort4
        #pragma unroll
        for (int m = 0; m < 8; ++m) {
            const int gr0 = m0 + m * 16 + quad * 4;
            const int bbi = gr0 >> 8, tl = gr0 & 255;
            const float4 rs4 = *(const float4*)(rs_row + gr0);
            #pragma unroll
            for (int n = 0; n < 4; ++n) {
                const int gcol = n0m + wn * 64 + n * 16 + mr;
                ushort4 o;
                o.x = f2bf_rne((float)acc[m][n][0] * rs4.x * wsc);
                o.y = f2bf_rne((float)acc[m][n][1] * rs4.y * wsc);
                o.z = f2bf_rne((float)acc[m][n][2] * rs4.z * wsc);
                o.w = f2bf_rne((float)acc[m][n][3] * rs4.w * wsc);
                *(ushort4*)(vt + (size_t)(bbi * 1024 + gcol) * 256 + tl) = o;
            }
        }
        return;
    }

    u16* ob = QKV ? ((mat == 0) ? qb : kb) : nullptr;
    #pragma unroll
    for (int m = 0; m < 8; ++m) {
        const int gr0 = m0 + m * 16 + quad * 4;
        #pragma unroll
        for (int r = 0; r < 4; ++r) {
            const int grow = gr0 + r;
            const float sc = rs_row[grow] * wsc;
            #pragma unroll
            for (int n = 0; n < 4; ++n) {
                const int gcol = n0m + wn * 64 + n * 16 + mr;
                const float val = (float)acc[m][n][r] * sc;
                if (QKV) {
                    ob[(size_t)grow * N + gcol] = f2bf_rne(val);
                } else {
                    outp[(size_t)grow * N + gcol] = val + bias[gcol];
                }
            }
        }
    }
}

// ---------------- LDS-free MFMA flash attention ----------------
// block = (b,h,qtile); wave = 16 q-rows. S^T = K Q^T (C layout: row=j, col=q)
// -> softmax reduces over regs+quads (2 shuffles) -> P^T->A-frag via 8
// shuffles + 4 selects per 32-j chunk -> O = P V with V^T B-frags from global.
// qt-major grid, heavy qtiles dispatch FIRST (LPT scheduling -- r5/r6 A/B
// proved this is worth ~36us over L2-colocating interleave).
__global__ __launch_bounds__(256) void attn_kernel(const u16* __restrict__ qb,
    const u16* __restrict__ kb, const u16* __restrict__ vt, float* __restrict__ y)
{
    const int t = threadIdx.x;
    const int qt = 3 - (int)(blockIdx.x >> 10);      // heavy qtiles dispatch first
    const int bh = blockIdx.x & 1023;
    const int b = bh >> 4, h = bh & 15;
    const int w = t >> 6, lane = t & 63;
    const int cl = lane & 15, quad = lane >> 4;
    const size_t gb = (size_t)(b * T) * 1024 + h * 64;             // q/k row-major base
    const u16* vtb = vt + (size_t)(b * 1024 + h * 64) * 256;       // V^T base

    const int qrow = qt * 64 + w * 16;
    const int jtiles = (qrow >> 4) + 1;              // causal: j-tiles 0..jtiles-1

    const u16* qrp = qb + gb + (size_t)(qrow + cl) * 1024 + quad * 8;
    bf16x8 qf0 = *(const bf16x8*)qrp;                // B-frag: n=q, k=d
    bf16x8 qf1 = *(const bf16x8*)(qrp + 32);

    f32x4 Sp[16];
    #pragma unroll
    for (int i2 = 0; i2 < 16; ++i2) Sp[i2] = (f32x4){0.f, 0.f, 0.f, 0.f};

    // --- S^T = K Q^T: A-frag m=j (lane cl = j-local), k=d ---
    const u16* krp = kb + gb + (size_t)cl * 1024 + quad * 8;
    #pragma unroll
    for (int jt = 0; jt < 16; ++jt) {
        if (jt < jtiles) {
            const u16* kp = krp + (size_t)(jt * 16) * 1024;
            bf16x8 kf0 = *(const bf16x8*)kp;
            bf16x8 kf1 = *(const bf16x8*)(kp + 32);
            Sp[jt] = __builtin_amdgcn_mfma_f32_16x16x32_bf16(kf0, qf0, Sp[jt], 0, 0, 0);
            Sp[jt] = __builtin_amdgcn_mfma_f32_16x16x32_bf16(kf1, qf1, Sp[jt], 0, 0, 0);
            if (jt == jtiles - 1) {                  // diagonal: mask j > q
                #pragma unroll
                for (int r = 0; r < 4; ++r)
                    if (quad * 4 + r > cl) Sp[jt][r] = -INFINITY;
            }
        }
    }

    // --- softmax over j (regs x quads); q = cl is lane-resident ---
    float mx = -INFINITY;
    #pragma unroll
    for (int jt = 0; jt < 16; ++jt) if (jt < jtiles) {
        #pragma unroll
        for (int r = 0; r < 4; ++r) mx = fmaxf(mx, Sp[jt][r]);
    }
    mx = fmaxf(mx, __shfl_xor(mx, 16));
    mx = fmaxf(mx, __shfl_xor(mx, 32));
    float l = 0.f;
    #pragma unroll
    for (int jt = 0; jt < 16; ++jt) if (jt < jtiles) {
        #pragma unroll
        for (int r = 0; r < 4; ++r) {
            float p = __expf(Sp[jt][r] - mx);
            Sp[jt][r] = p;
            l += p;
        }
    }
    l += __shfl_xor(l, 16);
    l += __shfl_xor(l, 32);

    // --- O = P V: A-frag built in-register from P^T via shuffles ---
    f32x4 O[4];
    #pragma unroll
    for (int i2 = 0; i2 < 4; ++i2) O[i2] = (f32x4){0.f, 0.f, 0.f, 0.f};

    const int s01 = ((quad & 1) << 5) + cl;          // src lane for frag slots 0-3
    const bool lo = quad < 2;                        // dest quads 0,1 use tile 2jc
    #pragma unroll
    for (int jc = 0; jc < 8; ++jc) {
        if (jc * 2 < jtiles) {
            int pk[2][2];                            // [tile][reg-pair] bf16x2
            #pragma unroll
            for (int s = 0; s < 2; ++s) {
                const f32x4 v = Sp[jc * 2 + s];      // tile >= jtiles is all-zero
                pk[s][0] = (int)((unsigned)f2bf_rne(v[0]) | ((unsigned)f2bf_rne(v[1]) << 16));
                pk[s][1] = (int)((unsigned)f2bf_rne(v[2]) | ((unsigned)f2bf_rne(v[3]) << 16));
            }
            int a0 = __shfl(pk[0][0], s01),      a1 = __shfl(pk[0][1], s01);
            int a2 = __shfl(pk[0][0], s01 + 16), a3 = __shfl(pk[0][1], s01 + 16);
            int b0 = __shfl(pk[1][0], s01),      b1 = __shfl(pk[1][1], s01);
            int b2 = __shfl(pk[1][0], s01 + 16), b3 = __shfl(pk[1][1], s01 + 16);
            union { int i[4]; bf16x8 v; } af;
            af.i[0] = lo ? a0 : b0;
            af.i[1] = lo ? a1 : b1;
            af.i[2] = lo ? a2 : b2;
            af.i[3] = lo ? a3 : b3;
            const u16* vp = vtb + (size_t)cl * 256 + jc * 32 + quad * 8;
            #pragma unroll
            for (int dt = 0; dt < 4; ++dt) {
                bf16x8 vf = *(const bf16x8*)(vp + (size_t)dt * 16 * 256);
                O[dt] = __builtin_amdgcn_mfma_f32_16x16x32_bf16(af.v, vf, O[dt], 0, 0, 0);
            }
        }
    }

    // --- normalize + store: O row = q-local = quad*4+r, col = d = dt*16+cl ---
    float inv[4];
    #pragma unroll
    for (int r = 0; r < 4; ++r) inv[r] = 1.0f / __shfl(l, quad * 4 + r);
    #pragma unroll
    for (int dt = 0; dt < 4; ++dt)
        #pragma unroll
        for (int r = 0; r < 4; ++r)
            y[gb + (size_t)(qrow + quad * 4 + r) * 1024 + dt * 16 + cl] = O[dt][r] * inv[r];
}

extern "C" void kernel_launch(void* const* d_in, const int* in_sizes, int n_in,
                              void* d_out, int out_size, void* d_ws, size_t ws_size,
                              hipStream_t stream) {
    (void)in_sizes; (void)n_in; (void)out_size; (void)ws_size;
    const float* x  = (const float*)d_in[0];
    const float* Wq = (const float*)d_in[1];
    const float* Wk = (const float*)d_in[2];
    const float* Wv = (const float*)d_in[3];
    const float* Wp = (const float*)d_in[4];
    const float* bp = (const float*)d_in[5];
    float* out = (float*)d_out;
    char* ws = (char*)d_ws;

    i8*     w8   = (i8*)(ws + W8_OFF);
    i8*     xq8  = (i8*)(ws + XQ8_OFF);
    float*  rsx  = (float*)(ws + RSX_OFF);
    float*  rsy  = (float*)(ws + RSY_OFF);
    double* wsum = (double*)(ws + WSUM_OFF);
    double* wpart= (double*)(ws + WPART_OFF);
    u16*    qb   = (u16*)(ws + QB_OFF);
    u16*    kb   = (u16*)(ws + KB_OFF);
    u16*    vt   = (u16*)(ws + VT_OFF);

    wsum1_kernel<<<256, 256, 0, stream>>>(Wq, Wk, Wv, Wp, wpart);
    wsum2_kernel<<<1, 256, 0, stream>>>(wpart, wsum);
    wquant_kernel<<<1024, 256, 0, stream>>>(Wq, Wk, Wv, Wp, wsum, w8);
    actquant_kernel<<<M, 256, 0, stream>>>(x, xq8, rsx);

    // fused q/k/v: 3 mats x 4 n-blocks (256 cols) x 128 m-blocks, 256 thr, 128x256 tiles
    gemm_kernel<true, 12><<<1536, 256, 0, stream>>>(xq8, w8, rsx, wsum, qb, kb, vt, nullptr, nullptr);

    attn_kernel<<<4 * 1024, 256, 0, stream>>>(qb, kb, vt, out);   // y -> d_out (scratch)

    actquant_kernel<<<M, 256, 0, stream>>>(out, xq8, rsy);        // y -> yq8
    gemm_kernel<false, 4><<<512, 256, 0, stream>>>(xq8, w8, rsy, wsum, nullptr, nullptr, nullptr, out, bp);
}

// Round 10
// 287.257 us; speedup vs baseline: 1.4898x; 1.0699x over previous
//
#include <hip/hip_runtime.h>
#include <math.h>

#define AS1 __attribute__((address_space(1)))
#define AS3 __attribute__((address_space(3)))

typedef unsigned short u16;
typedef signed char i8;
typedef short bf16x8 __attribute__((ext_vector_type(8)));
typedef float f32x4 __attribute__((ext_vector_type(4)));
typedef int i32x4 __attribute__((ext_vector_type(4)));

static constexpr int BB = 64, T = 256, C = 1024, H = 16, HD = 64;
static constexpr int M = BB * T;          // 16384 token rows
static constexpr float EPSF = 1e-5f;

// ---- workspace layout (bytes) ----
static constexpr size_t W8_OFF   = 0;                    // 4 x 1M i8 = 4 MiB frag-packed ternary weights
static constexpr size_t XQ8_OFF  = 4ull  << 20;          // 16M i8 = 16 MiB (reused for yq)
static constexpr size_t RSX_OFF  = 20ull << 20;          // 16384 f32
static constexpr size_t RSY_OFF  = (20ull << 20) + (64 << 10);
static constexpr size_t WSUM_OFF = (20ull << 20) + (128 << 10);   // 4 f64
static constexpr size_t WPART_OFF= WSUM_OFF + 64;                 // 256 f64
static constexpr size_t QB_OFF   = 21ull << 20;          // 32 MiB bf16
static constexpr size_t KB_OFF   = 53ull << 20;          // 32 MiB bf16
static constexpr size_t VT_OFF   = 85ull << 20;          // 32 MiB bf16 V^T [b][h*64+d][tloc]

// round-to-nearest-even f32 -> bf16 bits (finite inputs)
__device__ __forceinline__ u16 f2bf_rne(float f) {
    unsigned x = __float_as_uint(f);
    unsigned r = x + 0x7FFF + ((x >> 16) & 1);
    return (u16)(r >> 16);
}

// ---------------- weight |w| sum, stage 1 (deterministic, f64) ----------------
__global__ __launch_bounds__(256) void wsum1_kernel(const float* __restrict__ Wq,
    const float* __restrict__ Wk, const float* __restrict__ Wv,
    const float* __restrict__ Wp, double* __restrict__ wpart)
{
    const int mat = blockIdx.x >> 6;
    const float* W = (mat == 0) ? Wq : (mat == 1) ? Wk : (mat == 2) ? Wv : Wp;
    const int t = threadIdx.x;
    const int base = (blockIdx.x & 63) * 256 + t;
    double s = 0.0;
    for (int i = 0; i < 64; ++i) s += (double)fabsf(W[base + (i << 14)]);
    #pragma unroll
    for (int off = 32; off >= 1; off >>= 1) s += __shfl_down(s, off);
    __shared__ double red[4];
    if ((t & 63) == 0) red[t >> 6] = s;
    __syncthreads();
    if (t == 0) wpart[blockIdx.x] = red[0] + red[1] + red[2] + red[3];
}

__global__ __launch_bounds__(256) void wsum2_kernel(const double* __restrict__ wpart,
                                                    double* __restrict__ wsum)
{
    const int t = threadIdx.x;
    double s = wpart[t];
    #pragma unroll
    for (int off = 32; off >= 1; off >>= 1) s += __shfl_down(s, off);
    if ((t & 63) == 0) wsum[t >> 6] = s;
}

// ---------------- ternary weight quantization -> frag-packed int8 ----------------
// Packed layout (16B granules): granule g = (nt*16 + kt)*64 + lane holds
// W[nt*16 + (lane&15)][kt*64 + (lane>>4)*16 .. +15], so a wave's MFMA B-frag
// bf[n] at k-tile kt is ONE fully coalesced 1KB global_load_dwordx4 -- B never
// touches LDS in the GEMM.
__global__ __launch_bounds__(256) void wquant_kernel(const float* __restrict__ Wq,
    const float* __restrict__ Wk, const float* __restrict__ Wv,
    const float* __restrict__ Wp, const double* __restrict__ wsum,
    i8* __restrict__ w8)
{
    const int mat = blockIdx.x >> 8;
    const float* W = (mat == 0) ? Wq : (mat == 1) ? Wk : (mat == 2) ? Wv : Wp;
    const float mean = (float)(wsum[mat] * (1.0 / 1048576.0));
    const float s = 1.0f / fmaxf(mean, EPSF);
    const int g = (blockIdx.x & 255) * 256 + threadIdx.x;   // granule 0..65535
    const int lane = g & 63, kt = (g >> 6) & 15, nt = g >> 10;
    const int row = nt * 16 + (lane & 15);
    const int k0 = kt * 64 + (lane >> 4) * 16;
    const float* src = W + (size_t)row * 1024 + k0;
    union { i8 b[16]; i32x4 v; } o;
    #pragma unroll
    for (int j = 0; j < 16; ++j)
        o.b[j] = (i8)(int)fminf(fmaxf(rintf(src[j] * s), -1.f), 1.f);
    *(i32x4*)(w8 + ((size_t)mat << 20) + (size_t)g * 16) = o.v;
}

// ---------------- per-token activation quantization -> int8 ----------------
__global__ __launch_bounds__(256) void actquant_kernel(const float* __restrict__ x,
    i8* __restrict__ xq, float* __restrict__ rs)
{
    const int row = blockIdx.x;
    const int t = threadIdx.x;
    float4 v = ((const float4*)(x + (size_t)row * C))[t];
    float m = fmaxf(fmaxf(fabsf(v.x), fabsf(v.y)), fmaxf(fabsf(v.z), fabsf(v.w)));
    #pragma unroll
    for (int off = 32; off >= 1; off >>= 1) m = fmaxf(m, __shfl_down(m, off));
    __shared__ float red[4];
    if ((t & 63) == 0) red[t >> 6] = m;
    __syncthreads();
    float mm = fmaxf(fmaxf(red[0], red[1]), fmaxf(red[2], red[3]));
    mm = fmaxf(mm, EPSF);
    const float s = 127.0f / mm;
    if (t == 0) rs[row] = mm / 127.0f;
    char4 o;
    o.x = (i8)(int)fminf(fmaxf(rintf(v.x * s), -128.f), 127.f);
    o.y = (i8)(int)fminf(fmaxf(rintf(v.y * s), -128.f), 127.f);
    o.z = (i8)(int)fminf(fmaxf(rintf(v.z * s), -128.f), 127.f);
    o.w = (i8)(int)fminf(fmaxf(rintf(v.w * s), -128.f), 127.f);
    ((char4*)(xq + (size_t)row * C))[t] = o;
}

// ---------------- int8 MFMA GEMM: out[M,1024] = A[M,1024] x W[1024,1024]^T ----------------
// r7 structure (kept): tile 128x256, 4 waves (1Mx4N), per-wave 128x64 output;
// two blocks co-reside per CU so one block's MFMAs cover the other's
// barrier/load phase. A: 4-deep LDS ring (4 x 8KB), XOR-swizzled via
// inverse-swizzled global source. B: direct from L2 via frag-packed w8.
// Exact i32 accumulation, numerics unchanged.
template<bool QKV, int NNB>
__global__ __launch_bounds__(256, 2) void gemm_kernel(const i8* __restrict__ A,
    const i8* __restrict__ w8, const float* __restrict__ rs_row,
    const double* __restrict__ wsum, u16* __restrict__ qb, u16* __restrict__ kb,
    u16* __restrict__ vt, float* __restrict__ outp, const float* __restrict__ bias)
{
    constexpr int K = 1024, N = 1024;
    constexpr int NT = 16;                           // K-tiles of 64
    __shared__ __align__(16) i8 Asm[4][128 * 64];    // 32 KiB total

    const int t = threadIdx.x;

    // bijective XCD swizzle (nwg % 8 == 0 for both grids)
    const int nwg = NNB * 128;
    const int wg = (int)blockIdx.x;
    const int swz = (wg & 7) * (nwg >> 3) + (wg >> 3);
    const int mb = swz / NNB, nb = swz % NNB;
    const int m0 = mb * 128;
    const int mat = QKV ? (nb >> 2) : 3;
    const int n0m = QKV ? ((nb & 3) * 256) : (nb * 256);   // col base within mat
    const i8* Bw = w8 + ((size_t)mat << 20);               // frag-packed weights

    const int lane = t & 63, wn = t >> 6;            // 4 waves, 1x4 grid
    const int mr = lane & 15, quad = lane >> 4;

    // A staging granules: g1=t, g2=t+256 (16B each, linear LDS dest).
    // logical source offset = inverse swizzle of the physical byte address.
    const int g1 = t, g2 = t + 256;
    const int L1 = (g1 * 16) ^ (((g1 >> 3) & 7) << 4);
    const int L2 = (g2 * 16) ^ (((g2 >> 3) & 7) << 4);
    const i8* a1 = A + (size_t)(m0 + (L1 >> 6)) * K + (L1 & 63);
    const i8* a2 = A + (size_t)(m0 + (L2 >> 6)) * K + (L2 & 63);

    // swizzled A fragment read offsets
    const int vvs = (mr >> 1) & 7;
    int aoff[8];
    #pragma unroll
    for (int m = 0; m < 8; ++m)
        aoff[m] = ((m * 16 + mr) * 64 + quad * 16) ^ (vvs << 4);

    // B frag base: granule ((nt*16+kt)*64+lane)*16
    const int ntb = (n0m >> 4) + wn * 4;
    const i8* bfp = Bw + (size_t)ntb * 16384 + (size_t)lane * 16;

    i32x4 acc[8][4];
    #pragma unroll
    for (int m = 0; m < 8; ++m)
        #pragma unroll
        for (int n = 0; n < 4; ++n) acc[m][n] = (i32x4){0, 0, 0, 0};

    // prologue: stage A tiles 0 and 1
    #pragma unroll
    for (int p = 0; p < 2; ++p) {
        const int k0 = p * 64;
        __builtin_amdgcn_global_load_lds((const AS1 void*)(a1 + k0), (AS3 void*)&Asm[p][g1 * 16], 16, 0, 0);
        __builtin_amdgcn_global_load_lds((const AS1 void*)(a2 + k0), (AS3 void*)&Asm[p][g2 * 16], 16, 0, 0);
    }
    asm volatile("s_waitcnt vmcnt(2)" ::: "memory");   // tile 0 landed; tile 1 in flight
    __builtin_amdgcn_s_barrier();
    __builtin_amdgcn_sched_barrier(0);

    for (int tt = 0; tt < NT; ++tt) {
        const i8* Ac = Asm[tt & 3];
        i8* An = Asm[(tt + 2) & 3];
        const int kn = (tt + 2) * 64;

        // B frags for this tile, straight from L2 (issued before the A-stage)
        i32x4 bf[4];
        #pragma unroll
        for (int n = 0; n < 4; ++n)
            bf[n] = *(const i32x4*)(bfp + (size_t)n * 16384 + tt * 1024);

        // stage A(t+2) into the ring
        if (tt < NT - 2) {
            __builtin_amdgcn_global_load_lds((const AS1 void*)(a1 + kn), (AS3 void*)&An[g1 * 16], 16, 0, 0);
            __builtin_amdgcn_global_load_lds((const AS1 void*)(a2 + kn), (AS3 void*)&An[g2 * 16], 16, 0, 0);
        }

        // A fragment reads from LDS
        i32x4 af[8];
        #pragma unroll
        for (int m = 0; m < 8; ++m) af[m] = *(const i32x4*)&Ac[aoff[m]];

        __builtin_amdgcn_s_setprio(1);
        #pragma unroll
        for (int m = 0; m < 8; ++m)
            #pragma unroll
            for (int n = 0; n < 4; ++n)
                acc[m][n] = __builtin_amdgcn_mfma_i32_16x16x64_i8(af[m], bf[n], acc[m][n], 0, 0, 0);
        __builtin_amdgcn_s_setprio(0);

        // tile boundary: stage(t+1) proven done via in-order retirement;
        // keep stage(t+2)'s 2 loads in flight
        if (tt < NT - 2) {
            asm volatile("s_waitcnt vmcnt(2)" ::: "memory");
        } else if (tt < NT - 1) {
            asm volatile("s_waitcnt vmcnt(0)" ::: "memory");
        }
        __builtin_amdgcn_s_barrier();
        __builtin_amdgcn_sched_barrier(0);
    }

    float wsc = fmaxf((float)(wsum[mat] * (1.0 / 1048576.0)), EPSF);
    if (QKV && mat == 0) wsc *= 0.125f;              // fold 1/sqrt(hd) into q scale

    if (QKV && mat == 2) {
        // V^T store: vt[(b*1024 + col)*256 + tloc], 4 consecutive tokens per ushort4
        #pragma unroll
        for (int m = 0; m < 8; ++m) {
            const int gr0 = m0 + m * 16 + quad * 4;
            const int bbi = gr0 >> 8, tl = gr0 & 255;
            const float4 rs4 = *(const float4*)(rs_row + gr0);
            #pragma unroll
            for (int n = 0; n < 4; ++n) {
                const int gcol = n0m + wn * 64 + n * 16 + mr;
                ushort4 o;
                o.x = f2bf_rne((float)acc[m][n][0] * rs4.x * wsc);
                o.y = f2bf_rne((float)acc[m][n][1] * rs4.y * wsc);
                o.z = f2bf_rne((float)acc[m][n][2] * rs4.z * wsc);
                o.w = f2bf_rne((float)acc[m][n][3] * rs4.w * wsc);
                *(ushort4*)(vt + (size_t)(bbi * 1024 + gcol) * 256 + tl) = o;
            }
        }
        return;
    }

    u16* ob = QKV ? ((mat == 0) ? qb : kb) : nullptr;
    #pragma unroll
    for (int m = 0; m < 8; ++m) {
        const int gr0 = m0 + m * 16 + quad * 4;
        #pragma unroll
        for (int r = 0; r < 4; ++r) {
            const int grow = gr0 + r;
            const float sc = rs_row[grow] * wsc;
            #pragma unroll
            for (int n = 0; n < 4; ++n) {
                const int gcol = n0m + wn * 64 + n * 16 + mr;
                const float val = (float)acc[m][n][r] * sc;
                if (QKV) {
                    ob[(size_t)grow * N + gcol] = f2bf_rne(val);
                } else {
                    outp[(size_t)grow * N + gcol] = val + bias[gcol];
                }
            }
        }
    }
}

// ---------------- MFMA flash attention with cooperative LDS panel staging ----------------
// block = (b,h,qtile); wave = 16 q-rows. r8: the r7 counters (MfmaUtil 4.5%,
// VALUBusy 28%, HBM 26%, ~60% stall) showed per-wave serial K/V global loads
// as the bottleneck, with 4 waves re-reading the same K panel. Now one 32KB
// LDS panel per block, staged twice via async global_load_lds:
//   stage K (cc-major [8cc][jtB*16 r][16B]) -> drain -> S from LDS
//   barrier -> stage V ([2*jtB cc][64 r][16B]) WHILE softmax runs on VALU
//   -> drain -> PV from LDS.
// Both layouts make frag ds_reads lane-row-consecutive => conflict-free with
// no swizzle. 32KB => LDS-cap 5 blocks/CU > reg-cap ~3: occupancy unchanged.
// All loop bounds are block-uniform multiples of 64 (no divergent barriers).
// Math bit-identical to r7.
__global__ __launch_bounds__(256) void attn_kernel(const u16* __restrict__ qb,
    const u16* __restrict__ kb, const u16* __restrict__ vt, float* __restrict__ y)
{
    __shared__ __align__(16) i8 panel[32768];
    const int t = threadIdx.x;
    const int qt = 3 - (int)(blockIdx.x >> 10);      // heavy qtiles dispatch first (LPT)
    const int bh = blockIdx.x & 1023;
    const int b = bh >> 4, h = bh & 15;
    const int w = t >> 6, lane = t & 63;
    const int cl = lane & 15, quad = lane >> 4;
    const size_t gb = (size_t)(b * T) * 1024 + h * 64;             // q/k row-major base
    const char* kpb = (const char*)(kb + gb);                      // K panel, row stride 2048B
    const char* vpb = (const char*)(vt + (size_t)(b * 1024 + h * 64) * 256);  // V^T, row stride 512B

    const int jtB   = qt * 4 + 4;                    // block j-tiles (max over waves)
    const int jtB16 = jtB << 4;                      // staged K rows
    const int jtB256= jtB << 8;                      // K cc-column bytes

    // ---- stage K panel: LDS [8 cc][jtB16 rows][16B] (linear, lane-consecutive) ----
    #pragma unroll
    for (int cc = 0; cc < 8; ++cc)
        for (int rr = t; rr < jtB16; rr += 256)      // bound is multiple of 64
            __builtin_amdgcn_global_load_lds(
                (const AS1 void*)(kpb + (size_t)rr * 2048 + cc * 16),
                (AS3 void*)&panel[cc * jtB256 + rr * 16], 16, 0, 0);

    const int qrow = qt * 64 + w * 16;
    const int jtiles = (qrow >> 4) + 1;              // causal: j-tiles 0..jtiles-1

    const u16* qrp = qb + gb + (size_t)(qrow + cl) * 1024 + quad * 8;
    bf16x8 qf0 = *(const bf16x8*)qrp;                // B-frag: n=q, k=d
    bf16x8 qf1 = *(const bf16x8*)(qrp + 32);

    asm volatile("s_waitcnt vmcnt(0)" ::: "memory");
    __syncthreads();

    f32x4 Sp[16];
    #pragma unroll
    for (int i2 = 0; i2 < 16; ++i2) Sp[i2] = (f32x4){0.f, 0.f, 0.f, 0.f};

    // --- S^T = K Q^T from LDS: A-frag m=j (lane cl = j-local), k=d ---
    #pragma unroll
    for (int jt = 0; jt < 16; ++jt) {
        if (jt < jtiles) {
            const i8* kp0 = &panel[quad * jtB256 + (jt * 16 + cl) * 16];
            bf16x8 kf0 = *(const bf16x8*)kp0;
            bf16x8 kf1 = *(const bf16x8*)(kp0 + 4 * jtB256);
            Sp[jt] = __builtin_amdgcn_mfma_f32_16x16x32_bf16(kf0, qf0, Sp[jt], 0, 0, 0);
            Sp[jt] = __builtin_amdgcn_mfma_f32_16x16x32_bf16(kf1, qf1, Sp[jt], 0, 0, 0);
            if (jt == jtiles - 1) {                  // diagonal: mask j > q
                #pragma unroll
                for (int r = 0; r < 4; ++r)
                    if (quad * 4 + r > cl) Sp[jt][r] = -INFINITY;
            }
        }
    }

    __syncthreads();                                 // all waves done reading K

    // ---- stage V panel over K: LDS [2*jtB cc][64 r][16B] (linear) ----
    {
        const int nv = jtB << 7;                     // jtB*128 granules, multiple of 256
        for (int g = t; g < nv; g += 256)
            __builtin_amdgcn_global_load_lds(
                (const AS1 void*)(vpb + (size_t)(g & 63) * 512 + (g >> 6) * 16),
                (AS3 void*)&panel[g * 16], 16, 0, 0);
    }

    // --- softmax over j (regs x quads) -- VALU work overlaps V staging flight ---
    float mx = -INFINITY;
    #pragma unroll
    for (int jt = 0; jt < 16; ++jt) if (jt < jtiles) {
        #pragma unroll
        for (int r = 0; r < 4; ++r) mx = fmaxf(mx, Sp[jt][r]);
    }
    mx = fmaxf(mx, __shfl_xor(mx, 16));
    mx = fmaxf(mx, __shfl_xor(mx, 32));
    float l = 0.f;
    #pragma unroll
    for (int jt = 0; jt < 16; ++jt) if (jt < jtiles) {
        #pragma unroll
        for (int r = 0; r < 4; ++r) {
            float p = __expf(Sp[jt][r] - mx);
            Sp[jt][r] = p;
            l += p;
        }
    }
    l += __shfl_xor(l, 16);
    l += __shfl_xor(l, 32);

    asm volatile("s_waitcnt vmcnt(0)" ::: "memory");
    __syncthreads();

    // --- O = P V from LDS: A-frag built in-register from P^T via shuffles ---
    f32x4 O[4];
    #pragma unroll
    for (int i2 = 0; i2 < 4; ++i2) O[i2] = (f32x4){0.f, 0.f, 0.f, 0.f};

    const int s01 = ((quad & 1) << 5) + cl;          // src lane for frag slots 0-3
    const bool lo = quad < 2;                        // dest quads 0,1 use tile 2jc
    #pragma unroll
    for (int jc = 0; jc < 8; ++jc) {
        if (jc * 2 < jtiles) {
            int pk[2][2];                            // [tile][reg-pair] bf16x2
            #pragma unroll
            for (int s = 0; s < 2; ++s) {
                const f32x4 v = Sp[jc * 2 + s];      // tile >= jtiles is all-zero
                pk[s][0] = (int)((unsigned)f2bf_rne(v[0]) | ((unsigned)f2bf_rne(v[1]) << 16));
                pk[s][1] = (int)((unsigned)f2bf_rne(v[2]) | ((unsigned)f2bf_rne(v[3]) << 16));
            }
            int a0 = __shfl(pk[0][0], s01),      a1 = __shfl(pk[0][1], s01);
            int a2 = __shfl(pk[0][0], s01 + 16), a3 = __shfl(pk[0][1], s01 + 16);
            int b0 = __shfl(pk[1][0], s01),      b1 = __shfl(pk[1][1], s01);
            int b2 = __shfl(pk[1][0], s01 + 16), b3 = __shfl(pk[1][1], s01 + 16);
            union { int i[4]; bf16x8 v; } af;
            af.i[0] = lo ? a0 : b0;
            af.i[1] = lo ? a1 : b1;
            af.i[2] = lo ? a2 : b2;
            af.i[3] = lo ? a3 : b3;
            const i8* vp = &panel[(4 * jc + quad) * 1024 + cl * 16];
            #pragma unroll
            for (int dt = 0; dt < 4; ++dt) {
                bf16x8 vf = *(const bf16x8*)(vp + dt * 256);
                O[dt] = __builtin_amdgcn_mfma_f32_16x16x32_bf16(af.v, vf, O[dt], 0, 0, 0);
            }
        }
    }

    // --- normalize + store: O row = q-local = quad*4+r, col = d = dt*16+cl ---
    float inv[4];
    #pragma unroll
    for (int r = 0; r < 4; ++r) inv[r] = 1.0f / __shfl(l, quad * 4 + r);
    #pragma unroll
    for (int dt = 0; dt < 4; ++dt)
        #pragma unroll
        for (int r = 0; r < 4; ++r)
            y[gb + (size_t)(qrow + quad * 4 + r) * 1024 + dt * 16 + cl] = O[dt][r] * inv[r];
}

extern "C" void kernel_launch(void* const* d_in, const int* in_sizes, int n_in,
                              void* d_out, int out_size, void* d_ws, size_t ws_size,
                              hipStream_t stream) {
    (void)in_sizes; (void)n_in; (void)out_size; (void)ws_size;
    const float* x  = (const float*)d_in[0];
    const float* Wq = (const float*)d_in[1];
    const float* Wk = (const float*)d_in[2];
    const float* Wv = (const float*)d_in[3];
    const float* Wp = (const float*)d_in[4];
    const float* bp = (const float*)d_in[5];
    float* out = (float*)d_out;
    char* ws = (char*)d_ws;

    i8*     w8   = (i8*)(ws + W8_OFF);
    i8*     xq8  = (i8*)(ws + XQ8_OFF);
    float*  rsx  = (float*)(ws + RSX_OFF);
    float*  rsy  = (float*)(ws + RSY_OFF);
    double* wsum = (double*)(ws + WSUM_OFF);
    double* wpart= (double*)(ws + WPART_OFF);
    u16*    qb   = (u16*)(ws + QB_OFF);
    u16*    kb   = (u16*)(ws + KB_OFF);
    u16*    vt   = (u16*)(ws + VT_OFF);

    wsum1_kernel<<<256, 256, 0, stream>>>(Wq, Wk, Wv, Wp, wpart);
    wsum2_kernel<<<1, 256, 0, stream>>>(wpart, wsum);
    wquant_kernel<<<1024, 256, 0, stream>>>(Wq, Wk, Wv, Wp, wsum, w8);
    actquant_kernel<<<M, 256, 0, stream>>>(x, xq8, rsx);

    // fused q/k/v: 3 mats x 4 n-blocks (256 cols) x 128 m-blocks, 256 thr, 128x256 tiles
    gemm_kernel<true, 12><<<1536, 256, 0, stream>>>(xq8, w8, rsx, wsum, qb, kb, vt, nullptr, nullptr);

    attn_kernel<<<4 * 1024, 256, 0, stream>>>(qb, kb, vt, out);   // y -> d_out (scratch)

    actquant_kernel<<<M, 256, 0, stream>>>(out, xq8, rsy);        // y -> yq8
    gemm_kernel<false, 4><<<512, 256, 0, stream>>>(xq8, w8, rsy, wsum, nullptr, nullptr, nullptr, out, bp);
}